// Round 1
// 25678.595 us; speedup vs baseline: 1.5324x; 1.5324x over previous
//
#include <hip/hip_runtime.h>
#include <hip/hip_bf16.h>
#include <hip/hip_fp16.h>
#include <math.h>

#define DIN   1068
#define DPAD  1088
#define HID   768
#define G4    3072
#define BM    128
#define BN    128
#define BK    16
#define NWG_SCAN 96
#define SLAB  2048

__device__ __forceinline__ float sigf(float x){ return 1.0f/(1.0f + expf(-x)); }

// ---------------- prep: doc offsets -> per-position index within doc ----------------
__global__ void k_prep(const int* __restrict__ doc_lens, int* __restrict__ pos_idx, int N){
    __shared__ int off[129];
    if (threadIdx.x == 0){
        int a = 0;
        for (int d = 0; d < 128; ++d){ off[d] = a; a += doc_lens[d]; }
        off[128] = a;
    }
    __syncthreads();
    for (int d = threadIdx.x; d < 128; d += blockDim.x){
        int s = off[d], e = off[d+1];
        for (int n = s; n < e && n < N; ++n) pos_idx[n] = n - s;
    }
}

// ---------------- x_doc = x + PE(pos) (fp32), rows offset +4, cols 1068->1088 ----------------
__global__ void k_fill_xdoc(const float* __restrict__ x, const int* __restrict__ pos_idx,
                            float* __restrict__ xd, int N){
    int idx = blockIdx.x*256 + threadIdx.x;
    int total = N * DPAD;
    if (idx >= total) return;
    int n = idx / DPAD;
    int d = idx - n*DPAD;
    float v = 0.f;
    if (d < DIN){
        int pos = pos_idx[n];
        int i2 = d & ~1;                      // 2*i for both sin (even d) and cos (odd d)
        float ex  = expf(-(float)i2 * (9.210340371976184f / 1068.0f)); // 10000^(-i2/1068)
        float ang = (float)pos * ex;
        v = x[(size_t)n*DIN + d] + ((d & 1) ? cosf(ang) : sinf(ang));
    }
    xd[(size_t)(n+4)*DPAD + d] = v;
}

// ---------------- repack conv weights [oc][d][t] -> [tau][oc][dpad] (fp32) ----------------
__global__ void k_repack_w(const float* __restrict__ w0, const float* __restrict__ w1,
                           const float* __restrict__ w2, float* __restrict__ wrep){
    int idx = blockIdx.x*256 + threadIdx.x;
    const int total = 15*256*DPAD;
    if (idx >= total) return;
    int d    = idx % DPAD;
    int rest = idx / DPAD;
    int oc   = rest % 256;
    int tau  = rest / 256;
    const float* w; int k, t;
    if (tau < 3)      { w = w0; k = 3; t = tau;     }
    else if (tau < 8) { w = w1; k = 5; t = tau - 3; }
    else              { w = w2; k = 7; t = tau - 8; }
    float v = 0.f;
    if (d < DIN) v = w[((size_t)oc*DIN + d)*k + t];
    wrep[(size_t)idx] = v;
}

// ---------------- fp32 tile GEMM core: acc += A(rows m0.., shifted/guarded) * B^T ----------------
// A: row-major [*, K] fp32; B pre-offset to tile row 0, row-major [128, K] fp32.
__device__ __forceinline__ void tile_accum(
    const float* __restrict__ A, const float* __restrict__ B,
    int K, int m0, int shift, int rowcap, int tid,
    float (&acc)[8][8], float (&As)[BK][BM], float (&Bs)[BK][BN])
{
    const int row = tid >> 1;
    const int seg = (tid & 1) * 8;
    const int ty  = tid >> 4, tx = tid & 15;
    for (int k0 = 0; k0 < K; k0 += BK){
        float4 a0 = make_float4(0.f,0.f,0.f,0.f), a1 = a0;
        int r = m0 + row + shift;
        if ((unsigned)r < (unsigned)rowcap){
            const float* p = A + (size_t)r*K + k0 + seg;
            a0 = *(const float4*)p;
            a1 = *(const float4*)(p+4);
        }
        const float* q = B + (size_t)row*K + k0 + seg;
        float4 b0 = *(const float4*)q;
        float4 b1 = *(const float4*)(q+4);
        As[seg+0][row]=a0.x; As[seg+1][row]=a0.y; As[seg+2][row]=a0.z; As[seg+3][row]=a0.w;
        As[seg+4][row]=a1.x; As[seg+5][row]=a1.y; As[seg+6][row]=a1.z; As[seg+7][row]=a1.w;
        Bs[seg+0][row]=b0.x; Bs[seg+1][row]=b0.y; Bs[seg+2][row]=b0.z; Bs[seg+3][row]=b0.w;
        Bs[seg+4][row]=b1.x; Bs[seg+5][row]=b1.y; Bs[seg+6][row]=b1.z; Bs[seg+7][row]=b1.w;
        __syncthreads();
        #pragma unroll
        for (int kk = 0; kk < BK; ++kk){
            float a[8], b[8];
            *(float4*)&a[0] = *(const float4*)&As[kk][ty*8];
            *(float4*)&a[4] = *(const float4*)&As[kk][ty*8+4];
            *(float4*)&b[0] = *(const float4*)&Bs[kk][tx*8];
            *(float4*)&b[4] = *(const float4*)&Bs[kk][tx*8+4];
            #pragma unroll
            for (int i = 0; i < 8; ++i)
                #pragma unroll
                for (int j = 0; j < 8; ++j)
                    acc[i][j] = fmaf(a[i], b[j], acc[i][j]);
        }
        __syncthreads();
    }
}

// ---------------- projection GEMM: C = A0*B0^T (+ A1*B1^T) + bias0 (+bias1); C fp32 or fp16 ----------------
template<bool CHALF>
__global__ __launch_bounds__(256) void k_proj_gemm(
    const float* __restrict__ A0, const float* __restrict__ B0,
    const float* __restrict__ A1, const float* __restrict__ B1,
    const float* __restrict__ bias0, const float* __restrict__ bias1,
    void* __restrict__ C, int M, int K, int ldc)
{
    __shared__ float As[BK][BM];
    __shared__ float Bs[BK][BN];
    float acc[8][8] = {};
    int tid = threadIdx.x;
    int m0 = blockIdx.x*BM;
    int n0 = blockIdx.y*BN;
    tile_accum(A0, B0 + (size_t)n0*K, K, m0, 0, M, tid, acc, As, Bs);
    if (A1) tile_accum(A1, B1 + (size_t)n0*K, K, m0, 0, M, tid, acc, As, Bs);
    int ty = tid>>4, tx = tid&15;
    float bv[8];
    #pragma unroll
    for (int j = 0; j < 8; ++j){
        int cn = n0 + tx*8 + j;
        bv[j] = bias0[cn] + (bias1 ? bias1[cn] : 0.f);
    }
    #pragma unroll
    for (int i = 0; i < 8; ++i){
        int gm = m0 + ty*8 + i;
        if (gm >= M) continue;
        if (CHALF){
            __half* crow = (__half*)C + (size_t)gm*ldc + n0 + tx*8;
            #pragma unroll
            for (int j = 0; j < 8; ++j) crow[j] = __float2half(acc[i][j] + bv[j]);
        } else {
            float* crow = (float*)C + (size_t)gm*ldc + n0 + tx*8;
            #pragma unroll
            for (int j = 0; j < 8; ++j) crow[j] = acc[i][j] + bv[j];
        }
    }
}

// ---------------- conv GEMM over taps + bias + LeakyReLU -> x_feat (fp32 A) ----------------
__global__ __launch_bounds__(256) void k_conv_gemm(
    const float* __restrict__ xd, const float* __restrict__ wrep,
    const float* __restrict__ cb0, const float* __restrict__ cb1, const float* __restrict__ cb2,
    float* __restrict__ x_feat, int N)
{
    __shared__ float As[BK][BM];
    __shared__ float Bs[BK][BN];
    float acc[8][8] = {};
    int tid = threadIdx.x;
    int m0  = blockIdx.x*BM;
    int gid = blockIdx.y;            // 0..5
    int g = gid >> 1, half = gid & 1;
    int kg = (g==0)?3:((g==1)?5:7);
    int p  = kg >> 1;
    int tb = (g==0)?0:((g==1)?3:8);
    for (int t = 0; t < kg; ++t){
        const float* B = wrep + ((size_t)(tb + t)*256 + half*128)*DPAD;
        tile_accum(xd, B, DPAD, m0, 4 + t - p, N + 8, tid, acc, As, Bs);
    }
    const float* cb = (g==0)?cb0:((g==1)?cb1:cb2);
    int ty = tid>>4, tx = tid&15;
    float bv[8];
    #pragma unroll
    for (int j = 0; j < 8; ++j) bv[j] = cb[half*128 + tx*8 + j];
    int colbase = g*256 + half*128 + tx*8;
    #pragma unroll
    for (int i = 0; i < 8; ++i){
        int gm = m0 + ty*8 + i;
        if (gm >= N) continue;
        float* crow = x_feat + (size_t)gm*HID + colbase;
        #pragma unroll
        for (int j = 0; j < 8; ++j){
            float y = acc[i][j] + bv[j];
            crow[j] = (y >= 0.f) ? y : 0.01f*y;
        }
    }
}

// ---------------- maxpool (stride1, same) over activated conv output ----------------
__global__ void k_pool(const float* __restrict__ xf, float* __restrict__ xp, int N){
    int idx = blockIdx.x*256 + threadIdx.x;
    if (idx >= N*HID) return;
    int n = idx / HID, ch = idx - n*HID;
    int p = (ch < 256) ? 1 : ((ch < 512) ? 2 : 3);
    float m = -INFINITY;
    for (int d = -p; d <= p; ++d){
        int r = n + d;
        if (0 <= r && r < N) m = fmaxf(m, xf[(size_t)r*HID + ch]);
    }
    xp[idx] = m;
}

// ---------------- chunked LSTM scan: 96 persistent WGs, W_hh in registers ----------------
// WG w owns h-indices w*8..w*8+7 (gate rows q*768 + w*8 + i); 16 chains batched per step.
// K is distributed over 8 lane-groups as INTERLEAVED float4 chunks (lane ks owns chunks
// j*8+ks): for fixed j the 8 groups read 32 consecutive floats = all 32 banks exactly
// once, with 8-lane same-address broadcast (free) -> conflict-free ds_read_b128.
//
// Cross-WG exchange protocol (this revision): NO __threadfence, NO acquire/release.
// On gfx950 the per-XCD L2s are non-coherent; agent-scope atomics bypass them (sc0/sc1)
// and are coherent at the MALL. So h_buf is moved entirely with RELAXED agent-scope
// atomic stores/loads, and the flags use RELAXED agent-scope atomics. Ordering
// (data-before-flag) is the s_waitcnt vmcnt(0) that __syncthreads() emits between the
// phase-3 stores and the flag store. This removes the buffer_wbl2/buffer_inv storm
// (previously: 2 fences x 4 waves + 1 buffer_inv per poll iteration, per WG per step)
// that made each of the ~994 serial steps cost ~31 us.
__global__ __launch_bounds__(256, 1) void k_scan(
    const __half* __restrict__ G1, const float* __restrict__ W_hh,
    float* __restrict__ h_all, __half* __restrict__ c_all,
    float* __restrict__ h_buf, unsigned int* __restrict__ flags,
    int N, int n_chunks)
{
    __shared__ float hs[16*HID];          // current h for all 16 chains
    __shared__ float gsm[4][8][17];       // per-wave reduced gate pre-acts (+1 pad)
    const int w    = blockIdx.x;
    const int t    = threadIdx.x;
    const int lane = t & 63;
    const int wv   = t >> 6;              // wave 0..3
    const int r_loc= lane & 7;            // i2*4 + q
    const int ks   = lane >> 3;           // k-slice 0..7 (interleaved float4 chunks)
    const int q    = r_loc & 3;
    const int i2   = r_loc >> 2;
    const int i_loc= wv*2 + i2;           // 0..7 local h index
    const int grow = q*HID + w*8 + i_loc; // global gate row
    float4 wreg4[24];
    {
        const float* wp = W_hh + (size_t)grow*HID;
        #pragma unroll
        for (int j = 0; j < 24; ++j)
            wreg4[j] = *(const float4*)(wp + (j*8 + ks)*4);
    }
    float cstate = 0.f;
    const int ci = t >> 4;                // cell-phase h index (t<128)
    const int cc = t & 15;                // cell-phase chain
    for (int s = 0; s < n_chunks; ++s){
        // 0. prefetch this step's G1 gates (independent of h -> overlaps phase 2)
        float g1v0=0.f, g1v1=0.f, g1v2=0.f, g1v3=0.f;
        int n = s*16 + cc;
        if (t < 128 && n < N){
            const __half* g1r = G1 + (size_t)n*G4 + w*8 + ci;
            g1v0 = __half2float(g1r[0]);
            g1v1 = __half2float(g1r[HID]);
            g1v2 = __half2float(g1r[2*HID]);
            g1v3 = __half2float(g1r[3*HID]);
        }
        // 1. stage h (ping-pong buffer) into LDS via coherent (sc1) 8B relaxed-atomic loads
        {
            const unsigned long long* hsrc =
                (const unsigned long long*)(h_buf + (size_t)(s & 1)*(16*HID));
            unsigned long long* hdst = (unsigned long long*)hs;
            for (int j = t; j < 16*HID/2; j += 256)
                hdst[j] = __hip_atomic_load(hsrc + j, __ATOMIC_RELAXED,
                                            __HIP_MEMORY_SCOPE_AGENT);
        }
        __syncthreads();
        // 2. partial dot per (row, k-slice): conflict-free b128 reads, shuffle-reduce
        for (int c = 0; c < 16; ++c){
            const float4* hp4 = (const float4*)(hs + c*HID);
            float pa = 0.f;
            #pragma unroll
            for (int j = 0; j < 24; ++j){
                float4 hv = hp4[j*8 + ks];
                pa = fmaf(wreg4[j].x, hv.x, pa);
                pa = fmaf(wreg4[j].y, hv.y, pa);
                pa = fmaf(wreg4[j].z, hv.z, pa);
                pa = fmaf(wreg4[j].w, hv.w, pa);
            }
            pa += __shfl_xor(pa, 8, 64);
            pa += __shfl_xor(pa, 16, 64);
            pa += __shfl_xor(pa, 32, 64);
            if (lane < 8) gsm[wv][lane][c] = pa;
        }
        __syncthreads();
        // 3. cell math: 128 threads = 8 h-indices x 16 chains
        if (t < 128 && n < N){
            int col = w*8 + ci;
            int wv2 = ci >> 1, i22 = ci & 1;
            float gI = gsm[wv2][i22*4+0][cc] + g1v0;
            float gF = gsm[wv2][i22*4+1][cc] + g1v1;
            float gG = gsm[wv2][i22*4+2][cc] + g1v2;
            float gO = gsm[wv2][i22*4+3][cc] + g1v3;
            float c2 = sigf(gF)*cstate + sigf(gI)*tanhf(gG);
            float h2 = sigf(gO)*tanhf(c2);
            cstate = c2;
            size_t rowoff = (size_t)(16 + n)*HID + col;
            h_all[rowoff] = h2;                       // plain (consumed after kernel end)
            c_all[rowoff] = __float2half(c2);         // plain (consumed after kernel end)
            __hip_atomic_store(h_buf + (size_t)((s+1)&1)*(16*HID) + cc*HID + col, h2,
                               __ATOMIC_RELAXED, __HIP_MEMORY_SCOPE_AGENT);
        }
        // 4. distributed flag barrier across the 96 WGs (relaxed agent atomics only).
        __syncthreads();                  // drains vmcnt: phase-3 sc1 stores are at MALL
        if (t == 0)
            __hip_atomic_store(&flags[w*16], (unsigned)(s + 1),
                               __ATOMIC_RELAXED, __HIP_MEMORY_SCOPE_AGENT);
        if (t < NWG_SCAN){
            while (__hip_atomic_load(&flags[t*16], __ATOMIC_RELAXED,
                                     __HIP_MEMORY_SCOPE_AGENT) < (unsigned)(s + 1))
                __builtin_amdgcn_s_sleep(2);
        }
        __syncthreads();                  // everyone saw all 96 flags -> step s data ready
    }
}

// ---------------- final two LSTM cells (forward + rev weights) ----------------
__global__ void k_cell(const float* __restrict__ g2, const float* __restrict__ g3,
                       const __half* __restrict__ c_all, float* __restrict__ out,
                       int n0, int Mslab, int N){
    int idx = blockIdx.x*256 + threadIdx.x;
    if (idx >= Mslab*HID) return;
    int nl = idx / HID, j = idx - nl*HID;
    int n = n0 + nl;
    const float* r2 = g2 + (size_t)nl*G4;
    float cp = __half2float(c_all[(size_t)(7 + n)*HID + j]);   // c[n-9] (16-row pad, -9)
    float c2 = sigf(r2[HID + j])*cp + sigf(r2[j])*tanhf(r2[2*HID + j]);
    out[(size_t)n*1536 + j] = sigf(r2[3*HID + j])*tanhf(c2);
    const float* r3 = g3 + (size_t)nl*G4;
    float cn = __half2float(c_all[(size_t)(25 + n)*HID + j]);  // c[n+9]
    float c3 = sigf(r3[HID + j])*cn + sigf(r3[j])*tanhf(r3[2*HID + j]);
    out[(size_t)n*1536 + HID + j] = sigf(r3[3*HID + j])*tanhf(c3);
}

extern "C" void kernel_launch(void* const* d_in, const int* in_sizes, int n_in,
                              void* d_out, int out_size, void* d_ws, size_t ws_size,
                              hipStream_t stream)
{
    const float* x     = (const float*)d_in[0];
    const int*   dl    = (const int*)  d_in[1];
    const float* cw0   = (const float*)d_in[2];
    const float* cb0   = (const float*)d_in[3];
    const float* cw1   = (const float*)d_in[4];
    const float* cb1   = (const float*)d_in[5];
    const float* cw2   = (const float*)d_in[6];
    const float* cb2   = (const float*)d_in[7];
    const float* W_ih  = (const float*)d_in[8];
    const float* W_hh  = (const float*)d_in[9];
    const float* b_ih  = (const float*)d_in[10];
    const float* b_hh  = (const float*)d_in[11];
    const float* W_ihr = (const float*)d_in[12];
    const float* W_hhr = (const float*)d_in[13];
    const float* b_ihr = (const float*)d_in[14];
    const float* b_hhr = (const float*)d_in[15];
    float* out = (float*)d_out;
    (void)in_sizes; (void)n_in;
    const int N = out_size / (2*HID);
    if (N <= 0) return;
    const int n_chunks = (N + 15)/16;
    const int N16 = n_chunks*16;

    // ---- lifetime-overlaid arena (peak ~234 MB) ----
    // R0 timeline: {xd fp32 + wrep} -> {x_pool} -> {h_all fp32 + c_all fp16}
    auto AL = [](size_t b){ return (b + 255) & ~(size_t)255; };
    const size_t szXd   = AL((size_t)(N+8)*DPAD*4);      // fp32 x_doc
    const size_t szW    = AL((size_t)15*256*DPAD*4);     // conv weights repacked
    const size_t szPool = AL((size_t)N*HID*4);           // x_pool
    const size_t szH    = AL((size_t)(N+32)*HID*4);      // h_all fp32
    const size_t szC    = AL((size_t)(N+32)*HID*2);      // c_all fp16
    size_t r0 = szXd + szW;
    if (szPool     > r0) r0 = szPool;
    if (szH + szC  > r0) r0 = szH + szC;
    const size_t szF    = AL((size_t)N*HID*4);           // x_feat (alive to end)
    size_t szG1 = AL((size_t)N16*G4*2);                  // fp16 G1 | later g2+g3
    const size_t szGG   = AL((size_t)SLAB*G4*4);
    if (2*szGG > szG1) szG1 = 2*szGG;
    const size_t szHB   = AL((size_t)2*16*HID*4);        // h ping-pong
    const size_t szFL   = AL((size_t)NWG_SCAN*16*4);     // flags, 64B-padded
    const size_t szPI   = AL((size_t)N*4);               // pos_idx

    char* wsb = (char*)d_ws;
    size_t off = 0;
    char* R0   = wsb;              off += r0;
    char* pF   = wsb + off;        off += szF;
    char* pG1  = wsb + off;        off += szG1;
    char* pHB  = wsb + off;        off += szHB;
    char* pFL  = wsb + off;        off += szFL;
    char* pPI  = wsb + off;        off += szPI;
    if (off > ws_size) return;     // workspace too small: fail loud (wrong answer), not a fault

    float*          xd    = (float*)R0;
    float*          wrep  = (float*)(R0 + szXd);
    float*          x_pool= (float*)R0;                  // overlays xd/wrep after conv
    float*          h_all = (float*)R0;                  // overlays x_pool after G1 GEMM
    __half*         c_all = (__half*)(R0 + szH);         // beside h_all in R0 slack
    float*          x_feat= (float*)pF;
    __half*         G1    = (__half*)pG1;
    float*          g2    = (float*)pG1;                 // overlays G1 after scan
    float*          g3    = (float*)(pG1 + szGG);
    float*          h_buf = (float*)pHB;
    unsigned*       flags = (unsigned*)pFL;
    int*            pos_idx = (int*)pPI;

    // ---- phase 1: x_doc (fp32) + conv weight repack + conv + pool ----
    hipMemsetAsync(xd, 0, (size_t)4*DPAD*4, stream);                       // top pad rows
    hipMemsetAsync(xd + (size_t)(N+4)*DPAD, 0, (size_t)4*DPAD*4, stream);  // bottom pad rows
    k_prep<<<1, 128, 0, stream>>>(dl, pos_idx, N);
    k_fill_xdoc<<<(N*DPAD + 255)/256, 256, 0, stream>>>(x, pos_idx, xd, N);
    k_repack_w<<<(15*256*DPAD + 255)/256, 256, 0, stream>>>(cw0, cw1, cw2, wrep);

    const int mt = (N + BM - 1)/BM;
    k_conv_gemm<<<dim3(mt, 6), 256, 0, stream>>>(xd, wrep, cb0, cb1, cb2, x_feat, N);
    k_pool<<<(N*HID + 255)/256, 256, 0, stream>>>(x_feat, x_pool, N);      // x_pool overlays xd

    // ---- phase 2: G1 = x_pool*W_ih^T + b_ih + b_hh (fp16 out) ----
    k_proj_gemm<true><<<dim3(mt, G4/BN), 256, 0, stream>>>(
        x_pool, W_ih, nullptr, nullptr, b_ih, b_hh, G1, N, HID, G4);

    // ---- phase 3: scan (h_all/c_all overlay x_pool region — pads zeroed only now) ----
    hipMemsetAsync(h_all, 0, (size_t)16*HID*4, stream);
    hipMemsetAsync(h_all + (size_t)(16+N)*HID, 0, (size_t)16*HID*4, stream);
    hipMemsetAsync(c_all, 0, (size_t)16*HID*2, stream);
    hipMemsetAsync(c_all + (size_t)(16+N)*HID, 0, (size_t)16*HID*2, stream);
    hipMemsetAsync(h_buf, 0, (size_t)2*16*HID*4, stream);
    hipMemsetAsync(flags, 0, szFL, stream);
    k_scan<<<NWG_SCAN, 256, 0, stream>>>(G1, W_hh, h_all, c_all, h_buf, flags, N, n_chunks);

    // ---- phase 4: final two cells, slabbed (g2/g3 overlay G1 region) ----
    for (int n0 = 0; n0 < N; n0 += SLAB){
        int ms  = (N - n0 < SLAB) ? (N - n0) : SLAB;
        int mts = (ms + BM - 1)/BM;
        k_proj_gemm<false><<<dim3(mts, G4/BN), 256, 0, stream>>>(
            x_feat + (size_t)n0*HID, W_ih, h_all + (size_t)(7+n0)*HID, W_hh,
            b_ih, b_hh, g2, ms, HID, G4);
        k_proj_gemm<false><<<dim3(mts, G4/BN), 256, 0, stream>>>(
            x_feat + (size_t)n0*HID, W_ihr, h_all + (size_t)(25+n0)*HID, W_hhr,
            b_ihr, b_hhr, g3, ms, HID, G4);
        k_cell<<<(ms*HID + 255)/256, 256, 0, stream>>>(g2, g3, c_all, out, n0, ms, N);
    }
}

// Round 2
// 14244.479 us; speedup vs baseline: 2.7624x; 1.8027x over previous
//
#include <hip/hip_runtime.h>
#include <hip/hip_bf16.h>
#include <hip/hip_fp16.h>
#include <math.h>

#define DIN   1068
#define DPAD  1088
#define HID   768
#define G4    3072
#define BM    128
#define BN    128
#define BK    16
#define NWG_SCAN 96
#define SLAB  2048
#define HPAD  776   // 768 + 8 halfs pad (keeps 16B alignment, breaks bank stride)

typedef _Float16 half8 __attribute__((ext_vector_type(8)));
typedef float    floatx4 __attribute__((ext_vector_type(4)));

__device__ __forceinline__ float sigf(float x){ return 1.0f/(1.0f + expf(-x)); }

// ---------------- prep: doc offsets -> per-position index within doc ----------------
__global__ void k_prep(const int* __restrict__ doc_lens, int* __restrict__ pos_idx, int N){
    __shared__ int off[129];
    if (threadIdx.x == 0){
        int a = 0;
        for (int d = 0; d < 128; ++d){ off[d] = a; a += doc_lens[d]; }
        off[128] = a;
    }
    __syncthreads();
    for (int d = threadIdx.x; d < 128; d += blockDim.x){
        int s = off[d], e = off[d+1];
        for (int n = s; n < e && n < N; ++n) pos_idx[n] = n - s;
    }
}

// ---------------- x_doc = x + PE(pos) (fp32), rows offset +4, cols 1068->1088 ----------------
__global__ void k_fill_xdoc(const float* __restrict__ x, const int* __restrict__ pos_idx,
                            float* __restrict__ xd, int N){
    int idx = blockIdx.x*256 + threadIdx.x;
    int total = N * DPAD;
    if (idx >= total) return;
    int n = idx / DPAD;
    int d = idx - n*DPAD;
    float v = 0.f;
    if (d < DIN){
        int pos = pos_idx[n];
        int i2 = d & ~1;                      // 2*i for both sin (even d) and cos (odd d)
        float ex  = expf(-(float)i2 * (9.210340371976184f / 1068.0f)); // 10000^(-i2/1068)
        float ang = (float)pos * ex;
        v = x[(size_t)n*DIN + d] + ((d & 1) ? cosf(ang) : sinf(ang));
    }
    xd[(size_t)(n+4)*DPAD + d] = v;
}

// ---------------- repack conv weights [oc][d][t] -> [tau][oc][dpad] (fp32) ----------------
__global__ void k_repack_w(const float* __restrict__ w0, const float* __restrict__ w1,
                           const float* __restrict__ w2, float* __restrict__ wrep){
    int idx = blockIdx.x*256 + threadIdx.x;
    const int total = 15*256*DPAD;
    if (idx >= total) return;
    int d    = idx % DPAD;
    int rest = idx / DPAD;
    int oc   = rest % 256;
    int tau  = rest / 256;
    const float* w; int k, t;
    if (tau < 3)      { w = w0; k = 3; t = tau;     }
    else if (tau < 8) { w = w1; k = 5; t = tau - 3; }
    else              { w = w2; k = 7; t = tau - 8; }
    float v = 0.f;
    if (d < DIN) v = w[((size_t)oc*DIN + d)*k + t];
    wrep[(size_t)idx] = v;
}

// ---------------- fp32 tile GEMM core: acc += A(rows m0.., shifted/guarded) * B^T ----------------
// A: row-major [*, K] fp32; B pre-offset to tile row 0, row-major [128, K] fp32.
__device__ __forceinline__ void tile_accum(
    const float* __restrict__ A, const float* __restrict__ B,
    int K, int m0, int shift, int rowcap, int tid,
    float (&acc)[8][8], float (&As)[BK][BM], float (&Bs)[BK][BN])
{
    const int row = tid >> 1;
    const int seg = (tid & 1) * 8;
    const int ty  = tid >> 4, tx = tid & 15;
    for (int k0 = 0; k0 < K; k0 += BK){
        float4 a0 = make_float4(0.f,0.f,0.f,0.f), a1 = a0;
        int r = m0 + row + shift;
        if ((unsigned)r < (unsigned)rowcap){
            const float* p = A + (size_t)r*K + k0 + seg;
            a0 = *(const float4*)p;
            a1 = *(const float4*)(p+4);
        }
        const float* q = B + (size_t)row*K + k0 + seg;
        float4 b0 = *(const float4*)q;
        float4 b1 = *(const float4*)(q+4);
        As[seg+0][row]=a0.x; As[seg+1][row]=a0.y; As[seg+2][row]=a0.z; As[seg+3][row]=a0.w;
        As[seg+4][row]=a1.x; As[seg+5][row]=a1.y; As[seg+6][row]=a1.z; As[seg+7][row]=a1.w;
        Bs[seg+0][row]=b0.x; Bs[seg+1][row]=b0.y; Bs[seg+2][row]=b0.z; Bs[seg+3][row]=b0.w;
        Bs[seg+4][row]=b1.x; Bs[seg+5][row]=b1.y; Bs[seg+6][row]=b1.z; Bs[seg+7][row]=b1.w;
        __syncthreads();
        #pragma unroll
        for (int kk = 0; kk < BK; ++kk){
            float a[8], b[8];
            *(float4*)&a[0] = *(const float4*)&As[kk][ty*8];
            *(float4*)&a[4] = *(const float4*)&As[kk][ty*8+4];
            *(float4*)&b[0] = *(const float4*)&Bs[kk][tx*8];
            *(float4*)&b[4] = *(const float4*)&Bs[kk][tx*8+4];
            #pragma unroll
            for (int i = 0; i < 8; ++i)
                #pragma unroll
                for (int j = 0; j < 8; ++j)
                    acc[i][j] = fmaf(a[i], b[j], acc[i][j]);
        }
        __syncthreads();
    }
}

// ---------------- projection GEMM: C = A0*B0^T (+ A1*B1^T) + bias0 (+bias1); C fp32 or fp16 ----------------
template<bool CHALF>
__global__ __launch_bounds__(256) void k_proj_gemm(
    const float* __restrict__ A0, const float* __restrict__ B0,
    const float* __restrict__ A1, const float* __restrict__ B1,
    const float* __restrict__ bias0, const float* __restrict__ bias1,
    void* __restrict__ C, int M, int K, int ldc)
{
    __shared__ float As[BK][BM];
    __shared__ float Bs[BK][BN];
    float acc[8][8] = {};
    int tid = threadIdx.x;
    int m0 = blockIdx.x*BM;
    int n0 = blockIdx.y*BN;
    tile_accum(A0, B0 + (size_t)n0*K, K, m0, 0, M, tid, acc, As, Bs);
    if (A1) tile_accum(A1, B1 + (size_t)n0*K, K, m0, 0, M, tid, acc, As, Bs);
    int ty = tid>>4, tx = tid&15;
    float bv[8];
    #pragma unroll
    for (int j = 0; j < 8; ++j){
        int cn = n0 + tx*8 + j;
        bv[j] = bias0[cn] + (bias1 ? bias1[cn] : 0.f);
    }
    #pragma unroll
    for (int i = 0; i < 8; ++i){
        int gm = m0 + ty*8 + i;
        if (gm >= M) continue;
        if (CHALF){
            __half* crow = (__half*)C + (size_t)gm*ldc + n0 + tx*8;
            #pragma unroll
            for (int j = 0; j < 8; ++j) crow[j] = __float2half(acc[i][j] + bv[j]);
        } else {
            float* crow = (float*)C + (size_t)gm*ldc + n0 + tx*8;
            #pragma unroll
            for (int j = 0; j < 8; ++j) crow[j] = acc[i][j] + bv[j];
        }
    }
}

// ---------------- conv GEMM over taps + bias + LeakyReLU -> x_feat (fp32 A) ----------------
__global__ __launch_bounds__(256) void k_conv_gemm(
    const float* __restrict__ xd, const float* __restrict__ wrep,
    const float* __restrict__ cb0, const float* __restrict__ cb1, const float* __restrict__ cb2,
    float* __restrict__ x_feat, int N)
{
    __shared__ float As[BK][BM];
    __shared__ float Bs[BK][BN];
    float acc[8][8] = {};
    int tid = threadIdx.x;
    int m0  = blockIdx.x*BM;
    int gid = blockIdx.y;            // 0..5
    int g = gid >> 1, half = gid & 1;
    int kg = (g==0)?3:((g==1)?5:7);
    int p  = kg >> 1;
    int tb = (g==0)?0:((g==1)?3:8);
    for (int t = 0; t < kg; ++t){
        const float* B = wrep + ((size_t)(tb + t)*256 + half*128)*DPAD;
        tile_accum(xd, B, DPAD, m0, 4 + t - p, N + 8, tid, acc, As, Bs);
    }
    const float* cb = (g==0)?cb0:((g==1)?cb1:cb2);
    int ty = tid>>4, tx = tid&15;
    float bv[8];
    #pragma unroll
    for (int j = 0; j < 8; ++j) bv[j] = cb[half*128 + tx*8 + j];
    int colbase = g*256 + half*128 + tx*8;
    #pragma unroll
    for (int i = 0; i < 8; ++i){
        int gm = m0 + ty*8 + i;
        if (gm >= N) continue;
        float* crow = x_feat + (size_t)gm*HID + colbase;
        #pragma unroll
        for (int j = 0; j < 8; ++j){
            float y = acc[i][j] + bv[j];
            crow[j] = (y >= 0.f) ? y : 0.01f*y;
        }
    }
}

// ---------------- maxpool (stride1, same) over activated conv output ----------------
__global__ void k_pool(const float* __restrict__ xf, float* __restrict__ xp, int N){
    int idx = blockIdx.x*256 + threadIdx.x;
    if (idx >= N*HID) return;
    int n = idx / HID, ch = idx - n*HID;
    int p = (ch < 256) ? 1 : ((ch < 512) ? 2 : 3);
    float m = -INFINITY;
    for (int d = -p; d <= p; ++d){
        int r = n + d;
        if (0 <= r && r < N) m = fmaxf(m, xf[(size_t)r*HID + ch]);
    }
    xp[idx] = m;
}

// ---------------- chunked LSTM scan: 96 persistent WGs, MFMA h-dot, fp16 h exchange ----------------
// WG w owns h-columns w*8..w*8+7 (32 gate rows: q*768 + w*8 + i, q=0..3, i=0..7).
// Per step the WG computes gates[32][16] = W_hh_rows[32][768] x h[768][16] with
// v_mfma_f32_16x16x32_f16: wave (mt,kh) does M-tile mt (16 rows) over K-half kh
// (384 = 12 k-steps). A (W_hh fp16) lives in 48 VGPRs; B = one ds_read_b128 of the
// fp16 h tile per MFMA (12/wave/step, vs 1536 b128/CU/step for the old VALU dot,
// which was LDS-return-BW-bound at ~7.7 us/step). K-halves are summed in phase 3
// via a small LDS gate buffer. h is exchanged in fp16 (halves stage bytes; matches B).
// Cross-WG protocol: relaxed agent-scope atomics only (proven in prev round).
__global__ __launch_bounds__(256, 1) void k_scan(
    const __half* __restrict__ G1, const float* __restrict__ W_hh,
    float* __restrict__ h_all, __half* __restrict__ c_all,
    __half* __restrict__ h_buf, unsigned int* __restrict__ flags,
    int N, int n_chunks)
{
    __shared__ __align__(16) __half hs16[16*HPAD];  // [chain][k] fp16, padded rows
    __shared__ float gbuf[2][32][17];               // [kh][row m][chain] partial gates
    const int w    = blockIdx.x;
    const int t    = threadIdx.x;
    const int lane = t & 63;
    const int wv   = t >> 6;              // wave 0..3
    const int mt   = wv & 1;              // M-tile (rows mt*16..mt*16+15)
    const int kh   = wv >> 1;             // K-half (k = kh*384 ..)
    const int mloc = lane & 15;           // A row within tile / B chain
    const int kb   = lane >> 4;           // k-subgroup (8 halfs each)
    // A fragments: W_hh rows in fp16, 12 k-steps x 8 halfs = 48 VGPRs
    const int mg   = mt*16 + mloc;        // local row 0..31
    const int qq   = mg >> 3;             // gate 0..3
    const int il   = mg & 7;              // h-index 0..7
    const int grow = qq*HID + w*8 + il;   // global W_hh row
    half8 areg[12];
    #pragma unroll
    for (int sk = 0; sk < 12; ++sk){
        const float* wp = W_hh + (size_t)grow*HID + kh*384 + sk*32 + kb*8;
        half8 a;
        #pragma unroll
        for (int e = 0; e < 8; ++e) a[e] = (_Float16)wp[e];
        areg[sk] = a;
    }
    float cstate = 0.f;
    const int ci = t >> 4;                // cell-phase h index (t<128)
    const int cc = t & 15;                // cell-phase chain
    for (int s = 0; s < n_chunks; ++s){
        // 0. prefetch this step's G1 gates (independent of h -> overlaps phases 1-2)
        float g1v0=0.f, g1v1=0.f, g1v2=0.f, g1v3=0.f;
        int n = s*16 + cc;
        if (t < 128 && n < N){
            const __half* g1r = G1 + (size_t)n*G4 + w*8 + ci;
            g1v0 = __half2float(g1r[0]);
            g1v1 = __half2float(g1r[HID]);
            g1v2 = __half2float(g1r[2*HID]);
            g1v3 = __half2float(g1r[3*HID]);
        }
        // 1. stage h (fp16 ping-pong) into LDS via coherent 8B relaxed-atomic loads
        {
            const unsigned long long* hsrc =
                (const unsigned long long*)(h_buf + (size_t)(s & 1)*(16*HPAD));
            unsigned long long* hdst = (unsigned long long*)hs16;
            for (int j = t; j < 16*HPAD/4; j += 256)
                hdst[j] = __hip_atomic_load(hsrc + j, __ATOMIC_RELAXED,
                                            __HIP_MEMORY_SCOPE_AGENT);
        }
        __syncthreads();
        // 2. MFMA: gates partial over this wave's K-half
        {
            floatx4 acc = {0.f, 0.f, 0.f, 0.f};
            const _Float16* hb = (const _Float16*)hs16;
            #pragma unroll
            for (int sk = 0; sk < 12; ++sk){
                int k0 = kh*384 + sk*32 + kb*8;
                half8 b = *(const half8*)(hb + (size_t)mloc*HPAD + k0);
                acc = __builtin_amdgcn_mfma_f32_16x16x32_f16(areg[sk], b, acc, 0, 0, 0);
            }
            // D layout: lane g*16+n holds D[mt*16 + g*4 + r][n], g = kb
            #pragma unroll
            for (int r = 0; r < 4; ++r)
                gbuf[kh][mt*16 + kb*4 + r][mloc] = acc[r];
        }
        __syncthreads();
        // 3. cell math: 128 threads = 8 h-indices x 16 chains
        if (t < 128 && n < N){
            int col = w*8 + ci;
            float gI = gbuf[0][0*8+ci][cc] + gbuf[1][0*8+ci][cc] + g1v0;
            float gF = gbuf[0][1*8+ci][cc] + gbuf[1][1*8+ci][cc] + g1v1;
            float gG = gbuf[0][2*8+ci][cc] + gbuf[1][2*8+ci][cc] + g1v2;
            float gO = gbuf[0][3*8+ci][cc] + gbuf[1][3*8+ci][cc] + g1v3;
            float c2 = sigf(gF)*cstate + sigf(gI)*tanhf(gG);
            float h2 = sigf(gO)*tanhf(c2);
            cstate = c2;
            size_t rowoff = (size_t)(16 + n)*HID + col;
            h_all[rowoff] = h2;                       // fp32 (phase-4 GEMM input)
            c_all[rowoff] = __float2half(c2);
            // pack 2 adjacent columns (ci, ci^1) -> one 4B relaxed-atomic store
            unsigned hb2 = (unsigned)__half_as_ushort(__float2half(h2));
            unsigned other = __shfl_xor(hb2, 16, 64);  // partner t^16 = same cc, ci^1
            if ((ci & 1) == 0){
                unsigned pk = hb2 | (other << 16);     // even col = low half
                unsigned* dst = (unsigned*)h_buf +
                    (((size_t)((s+1)&1)*(16*HPAD) + (size_t)cc*HPAD + col) >> 1);
                __hip_atomic_store(dst, pk, __ATOMIC_RELAXED, __HIP_MEMORY_SCOPE_AGENT);
            }
        }
        // 4. distributed flag barrier across the 96 WGs (relaxed agent atomics only)
        __syncthreads();                  // drains vmcnt: phase-3 stores are at MALL
        if (t == 0)
            __hip_atomic_store(&flags[w*16], (unsigned)(s + 1),
                               __ATOMIC_RELAXED, __HIP_MEMORY_SCOPE_AGENT);
        if (t < NWG_SCAN){
            while (__hip_atomic_load(&flags[t*16], __ATOMIC_RELAXED,
                                     __HIP_MEMORY_SCOPE_AGENT) < (unsigned)(s + 1))
                __builtin_amdgcn_s_sleep(2);
        }
        __syncthreads();                  // everyone saw all 96 flags -> step s data ready
    }
}

// ---------------- final two LSTM cells (forward + rev weights) ----------------
__global__ void k_cell(const float* __restrict__ g2, const float* __restrict__ g3,
                       const __half* __restrict__ c_all, float* __restrict__ out,
                       int n0, int Mslab, int N){
    int idx = blockIdx.x*256 + threadIdx.x;
    if (idx >= Mslab*HID) return;
    int nl = idx / HID, j = idx - nl*HID;
    int n = n0 + nl;
    const float* r2 = g2 + (size_t)nl*G4;
    float cp = __half2float(c_all[(size_t)(7 + n)*HID + j]);   // c[n-9] (16-row pad, -9)
    float c2 = sigf(r2[HID + j])*cp + sigf(r2[j])*tanhf(r2[2*HID + j]);
    out[(size_t)n*1536 + j] = sigf(r2[3*HID + j])*tanhf(c2);
    const float* r3 = g3 + (size_t)nl*G4;
    float cn = __half2float(c_all[(size_t)(25 + n)*HID + j]);  // c[n+9]
    float c3 = sigf(r3[HID + j])*cn + sigf(r3[j])*tanhf(r3[2*HID + j]);
    out[(size_t)n*1536 + HID + j] = sigf(r3[3*HID + j])*tanhf(c3);
}

extern "C" void kernel_launch(void* const* d_in, const int* in_sizes, int n_in,
                              void* d_out, int out_size, void* d_ws, size_t ws_size,
                              hipStream_t stream)
{
    const float* x     = (const float*)d_in[0];
    const int*   dl    = (const int*)  d_in[1];
    const float* cw0   = (const float*)d_in[2];
    const float* cb0   = (const float*)d_in[3];
    const float* cw1   = (const float*)d_in[4];
    const float* cb1   = (const float*)d_in[5];
    const float* cw2   = (const float*)d_in[6];
    const float* cb2   = (const float*)d_in[7];
    const float* W_ih  = (const float*)d_in[8];
    const float* W_hh  = (const float*)d_in[9];
    const float* b_ih  = (const float*)d_in[10];
    const float* b_hh  = (const float*)d_in[11];
    const float* W_ihr = (const float*)d_in[12];
    const float* W_hhr = (const float*)d_in[13];
    const float* b_ihr = (const float*)d_in[14];
    const float* b_hhr = (const float*)d_in[15];
    float* out = (float*)d_out;
    (void)in_sizes; (void)n_in;
    const int N = out_size / (2*HID);
    if (N <= 0) return;
    const int n_chunks = (N + 15)/16;
    const int N16 = n_chunks*16;

    // ---- lifetime-overlaid arena (peak ~234 MB) ----
    // R0 timeline: {xd fp32 + wrep} -> {x_pool} -> {h_all fp32 + c_all fp16}
    auto AL = [](size_t b){ return (b + 255) & ~(size_t)255; };
    const size_t szXd   = AL((size_t)(N+8)*DPAD*4);      // fp32 x_doc
    const size_t szW    = AL((size_t)15*256*DPAD*4);     // conv weights repacked
    const size_t szPool = AL((size_t)N*HID*4);           // x_pool
    const size_t szH    = AL((size_t)(N+32)*HID*4);      // h_all fp32
    const size_t szC    = AL((size_t)(N+32)*HID*2);      // c_all fp16
    size_t r0 = szXd + szW;
    if (szPool     > r0) r0 = szPool;
    if (szH + szC  > r0) r0 = szH + szC;
    const size_t szF    = AL((size_t)N*HID*4);           // x_feat (alive to end)
    size_t szG1 = AL((size_t)N16*G4*2);                  // fp16 G1 | later g2+g3
    const size_t szGG   = AL((size_t)SLAB*G4*4);
    if (2*szGG > szG1) szG1 = 2*szGG;
    const size_t szHB   = AL((size_t)2*16*HPAD*2);       // h ping-pong (fp16, padded rows)
    const size_t szFL   = AL((size_t)NWG_SCAN*16*4);     // flags, 64B-padded
    const size_t szPI   = AL((size_t)N*4);               // pos_idx

    char* wsb = (char*)d_ws;
    size_t off = 0;
    char* R0   = wsb;              off += r0;
    char* pF   = wsb + off;        off += szF;
    char* pG1  = wsb + off;        off += szG1;
    char* pHB  = wsb + off;        off += szHB;
    char* pFL  = wsb + off;        off += szFL;
    char* pPI  = wsb + off;        off += szPI;
    if (off > ws_size) return;     // workspace too small: fail loud (wrong answer), not a fault

    float*          xd    = (float*)R0;
    float*          wrep  = (float*)(R0 + szXd);
    float*          x_pool= (float*)R0;                  // overlays xd/wrep after conv
    float*          h_all = (float*)R0;                  // overlays x_pool after G1 GEMM
    __half*         c_all = (__half*)(R0 + szH);         // beside h_all in R0 slack
    float*          x_feat= (float*)pF;
    __half*         G1    = (__half*)pG1;
    float*          g2    = (float*)pG1;                 // overlays G1 after scan
    float*          g3    = (float*)(pG1 + szGG);
    __half*         h_buf = (__half*)pHB;
    unsigned*       flags = (unsigned*)pFL;
    int*            pos_idx = (int*)pPI;

    // ---- phase 1: x_doc (fp32) + conv weight repack + conv + pool ----
    hipMemsetAsync(xd, 0, (size_t)4*DPAD*4, stream);                       // top pad rows
    hipMemsetAsync(xd + (size_t)(N+4)*DPAD, 0, (size_t)4*DPAD*4, stream);  // bottom pad rows
    k_prep<<<1, 128, 0, stream>>>(dl, pos_idx, N);
    k_fill_xdoc<<<(N*DPAD + 255)/256, 256, 0, stream>>>(x, pos_idx, xd, N);
    k_repack_w<<<(15*256*DPAD + 255)/256, 256, 0, stream>>>(cw0, cw1, cw2, wrep);

    const int mt = (N + BM - 1)/BM;
    k_conv_gemm<<<dim3(mt, 6), 256, 0, stream>>>(xd, wrep, cb0, cb1, cb2, x_feat, N);
    k_pool<<<(N*HID + 255)/256, 256, 0, stream>>>(x_feat, x_pool, N);      // x_pool overlays xd

    // ---- phase 2: G1 = x_pool*W_ih^T + b_ih + b_hh (fp16 out) ----
    k_proj_gemm<true><<<dim3(mt, G4/BN), 256, 0, stream>>>(
        x_pool, W_ih, nullptr, nullptr, b_ih, b_hh, G1, N, HID, G4);

    // ---- phase 3: scan (h_all/c_all overlay x_pool region — pads zeroed only now) ----
    hipMemsetAsync(h_all, 0, (size_t)16*HID*4, stream);
    hipMemsetAsync(h_all + (size_t)(16+N)*HID, 0, (size_t)16*HID*4, stream);
    hipMemsetAsync(c_all, 0, (size_t)16*HID*2, stream);
    hipMemsetAsync(c_all + (size_t)(16+N)*HID, 0, (size_t)16*HID*2, stream);
    hipMemsetAsync(h_buf, 0, (size_t)2*16*HPAD*2, stream);
    hipMemsetAsync(flags, 0, szFL, stream);
    k_scan<<<NWG_SCAN, 256, 0, stream>>>(G1, W_hh, h_all, c_all, h_buf, flags, N, n_chunks);

    // ---- phase 4: final two cells, slabbed (g2/g3 overlay G1 region) ----
    for (int n0 = 0; n0 < N; n0 += SLAB){
        int ms  = (N - n0 < SLAB) ? (N - n0) : SLAB;
        int mts = (ms + BM - 1)/BM;
        k_proj_gemm<false><<<dim3(mts, G4/BN), 256, 0, stream>>>(
            x_feat + (size_t)n0*HID, W_ih, h_all + (size_t)(7+n0)*HID, W_hh,
            b_ih, b_hh, g2, ms, HID, G4);
        k_proj_gemm<false><<<dim3(mts, G4/BN), 256, 0, stream>>>(
            x_feat + (size_t)n0*HID, W_ihr, h_all + (size_t)(25+n0)*HID, W_hhr,
            b_ihr, b_hhr, g3, ms, HID, G4);
        k_cell<<<(ms*HID + 255)/256, 256, 0, stream>>>(g2, g3, c_all, out, n0, ms, N);
    }
}

// Round 5
// 8256.509 us; speedup vs baseline: 4.7658x; 1.7252x over previous
//
#include <hip/hip_runtime.h>
#include <hip/hip_bf16.h>
#include <hip/hip_fp16.h>
#include <math.h>

#define DIN   1068
#define DPAD  1088
#define HID   768
#define G4    3072
#define NWG_SCAN 96
#define SLAB  2048
#define HPAD  776   // 768 + 8 halfs pad for scan LDS
#define GBM   128
#define GBN   128
#define AROWP 40    // LDS row pitch in halfs: 32 + 8 pad

typedef _Float16 half8 __attribute__((ext_vector_type(8)));
typedef float    floatx4 __attribute__((ext_vector_type(4)));

__device__ __forceinline__ float sigf(float x){ return 1.0f/(1.0f + expf(-x)); }

// ---------------- prep: doc offsets -> per-position index within doc ----------------
__global__ void k_prep(const int* __restrict__ doc_lens, int* __restrict__ pos_idx, int N){
    __shared__ int off[129];
    if (threadIdx.x == 0){
        int a = 0;
        for (int d = 0; d < 128; ++d){ off[d] = a; a += doc_lens[d]; }
        off[128] = a;
    }
    __syncthreads();
    for (int d = threadIdx.x; d < 128; d += blockDim.x){
        int s = off[d], e = off[d+1];
        for (int n = s; n < e && n < N; ++n) pos_idx[n] = n - s;
    }
}

// ---------------- x_doc = x + PE(pos) (fp32), rows offset +4, cols 1068->1088 ----------------
__global__ void k_fill_xdoc(const float* __restrict__ x, const int* __restrict__ pos_idx,
                            float* __restrict__ xd, int N){
    int idx = blockIdx.x*256 + threadIdx.x;
    int total = N * DPAD;
    if (idx >= total) return;
    int n = idx / DPAD;
    int d = idx - n*DPAD;
    float v = 0.f;
    if (d < DIN){
        int pos = pos_idx[n];
        int i2 = d & ~1;                      // 2*i for both sin (even d) and cos (odd d)
        float ex  = expf(-(float)i2 * (9.210340371976184f / 1068.0f)); // 10000^(-i2/1068)
        float ang = (float)pos * ex;
        v = x[(size_t)n*DIN + d] + ((d & 1) ? cosf(ang) : sinf(ang));
    }
    xd[(size_t)(n+4)*DPAD + d] = v;
}

// ---------------- repack conv weights [oc][d][t] -> [tau][oc][dpad] (fp32) ----------------
__global__ void k_repack_w(const float* __restrict__ w0, const float* __restrict__ w1,
                           const float* __restrict__ w2, float* __restrict__ wrep){
    int idx = blockIdx.x*256 + threadIdx.x;
    const int total = 15*256*DPAD;
    if (idx >= total) return;
    int d    = idx % DPAD;
    int rest = idx / DPAD;
    int oc   = rest % 256;
    int tau  = rest / 256;
    const float* w; int k, t;
    if (tau < 3)      { w = w0; k = 3; t = tau;     }
    else if (tau < 8) { w = w1; k = 5; t = tau - 3; }
    else              { w = w2; k = 7; t = tau - 8; }
    float v = 0.f;
    if (d < DIN) v = w[((size_t)oc*DIN + d)*k + t];
    wrep[(size_t)idx] = v;
}

// ---------------- MFMA tile core over fp32 operands ----------------
// A,B fp32 row-major [*, K]; B pre-offset to its 128-row block. K % 32 == 0.
// Staging converts fp32 -> fp16 {hi[,lo]} in LDS. SPLIT=true computes
// hi*hi + hi*lo + lo*hi (3 MFMAs, fp32-equivalent precision, rel err ~2^-22);
// SPLIT=false computes hi*hi only (plain fp16 precision).
// 256 thr = 4 waves in 2x2, per-wave 64x64 output as 4x4 frags of 16x16x32_f16.
// Operand layout validated on HW by rounds 1-3: A/B lane l: row (l&15), k-base
// (l>>4)*8; D: col = lane&15, row = (lane>>4)*4 + r.
template<bool SPLIT>
__device__ __forceinline__ void mfma_core(
    const float* __restrict__ A, const float* __restrict__ B, int K,
    int m0, int shift, int rowcap, int tid, floatx4 (&acc)[4][4],
    _Float16* __restrict__ Ahi, _Float16* __restrict__ Alo,
    _Float16* __restrict__ Bhi, _Float16* __restrict__ Blo)
{
    const int st_r = tid >> 1;            // staged row 0..127
    const int st_s = (tid & 1) * 16;      // k-offset 0 or 16 (floats)
    const int wv = tid >> 6, lane = tid & 63;
    const int wr = wv >> 1, wc = wv & 1;
    const int mloc = lane & 15, kb = lane >> 4;
    for (int k0 = 0; k0 < K; k0 += 32){
        // ---- stage A (guarded rows) ----
        {
            float av[16] = {};
            int r = m0 + st_r + shift;
            if ((unsigned)r < (unsigned)rowcap){
                const float* pa = A + (size_t)r*K + k0 + st_s;
                *(float4*)&av[0]  = *(const float4*)pa;
                *(float4*)&av[4]  = *(const float4*)(pa+4);
                *(float4*)&av[8]  = *(const float4*)(pa+8);
                *(float4*)&av[12] = *(const float4*)(pa+12);
            }
            #pragma unroll
            for (int g = 0; g < 2; ++g){
                half8 hh, hl;
                #pragma unroll
                for (int e = 0; e < 8; ++e){
                    float f = av[g*8+e];
                    _Float16 h = (_Float16)f;
                    hh[e] = h;
                    if (SPLIT) hl[e] = (_Float16)(f - (float)h);
                }
                *(half8*)&Ahi[st_r*AROWP + st_s + g*8] = hh;
                if (SPLIT) *(half8*)&Alo[st_r*AROWP + st_s + g*8] = hl;
            }
        }
        // ---- stage B (always valid) ----
        {
            float bv[16];
            const float* pb = B + (size_t)st_r*K + k0 + st_s;
            *(float4*)&bv[0]  = *(const float4*)pb;
            *(float4*)&bv[4]  = *(const float4*)(pb+4);
            *(float4*)&bv[8]  = *(const float4*)(pb+8);
            *(float4*)&bv[12] = *(const float4*)(pb+12);
            #pragma unroll
            for (int g = 0; g < 2; ++g){
                half8 hh, hl;
                #pragma unroll
                for (int e = 0; e < 8; ++e){
                    float f = bv[g*8+e];
                    _Float16 h = (_Float16)f;
                    hh[e] = h;
                    if (SPLIT) hl[e] = (_Float16)(f - (float)h);
                }
                *(half8*)&Bhi[st_r*AROWP + st_s + g*8] = hh;
                if (SPLIT) *(half8*)&Blo[st_r*AROWP + st_s + g*8] = hl;
            }
        }
        __syncthreads();
        half8 afh[4], bfh[4], afl[4], bfl[4];
        #pragma unroll
        for (int i = 0; i < 4; ++i){
            afh[i] = *(const half8*)&Ahi[(wr*64 + i*16 + mloc)*AROWP + kb*8];
            bfh[i] = *(const half8*)&Bhi[(wc*64 + i*16 + mloc)*AROWP + kb*8];
            if (SPLIT){
                afl[i] = *(const half8*)&Alo[(wr*64 + i*16 + mloc)*AROWP + kb*8];
                bfl[i] = *(const half8*)&Blo[(wc*64 + i*16 + mloc)*AROWP + kb*8];
            }
        }
        #pragma unroll
        for (int i = 0; i < 4; ++i)
            #pragma unroll
            for (int j = 0; j < 4; ++j){
                acc[i][j] = __builtin_amdgcn_mfma_f32_16x16x32_f16(afh[i], bfh[j], acc[i][j], 0, 0, 0);
                if (SPLIT){
                    acc[i][j] = __builtin_amdgcn_mfma_f32_16x16x32_f16(afh[i], bfl[j], acc[i][j], 0, 0, 0);
                    acc[i][j] = __builtin_amdgcn_mfma_f32_16x16x32_f16(afl[i], bfh[j], acc[i][j], 0, 0, 0);
                }
            }
        __syncthreads();
    }
}

// ---------------- split-precision GEMM: C = A0*B0^T + bias0 (+bias1); fp32-quality ----------------
template<bool CHALF>
__global__ __launch_bounds__(256) void k_gemm_split(
    const float* __restrict__ A0, const float* __restrict__ B0,
    const float* __restrict__ bias0, const float* __restrict__ bias1,
    void* __restrict__ C, int M, int K, int ldc)
{
    __shared__ _Float16 Ahi[GBM*AROWP], Alo[GBM*AROWP];
    __shared__ _Float16 Bhi[GBN*AROWP], Blo[GBN*AROWP];
    floatx4 zz = {0.f, 0.f, 0.f, 0.f};
    floatx4 acc[4][4];
    #pragma unroll
    for (int i = 0; i < 4; ++i)
        #pragma unroll
        for (int j = 0; j < 4; ++j) acc[i][j] = zz;
    const int tid = threadIdx.x;
    const int m0 = blockIdx.x*GBM;
    const int n0 = blockIdx.y*GBN;
    mfma_core<true>(A0, B0 + (size_t)n0*K, K, m0, 0, M, tid, acc, Ahi, Alo, Bhi, Blo);
    const int wv = tid >> 6, lane = tid & 63;
    const int wr = wv >> 1, wc = wv & 1;
    const int mloc = lane & 15, kb = lane >> 4;
    float bv[4];
    #pragma unroll
    for (int j = 0; j < 4; ++j){
        int cn = n0 + wc*64 + j*16 + mloc;
        bv[j] = bias0[cn] + (bias1 ? bias1[cn] : 0.f);
    }
    #pragma unroll
    for (int i = 0; i < 4; ++i){
        #pragma unroll
        for (int r = 0; r < 4; ++r){
            int gm = m0 + wr*64 + i*16 + kb*4 + r;
            if (gm >= M) continue;
            #pragma unroll
            for (int j = 0; j < 4; ++j){
                int cn = n0 + wc*64 + j*16 + mloc;
                float v = acc[i][j][r] + bv[j];
                if (CHALF) ((__half*)C)[(size_t)gm*ldc + cn] = __float2half(v);
                else       ((float*)C)[(size_t)gm*ldc + cn] = v;
            }
        }
    }
}

// ---------------- plain fp16 GEMM (fp32 in): C = A0*B0^T + A1*B1^T + bias0 + bias1 ----------------
__global__ __launch_bounds__(256) void k_gemm_plain2(
    const float* __restrict__ A0, const float* __restrict__ B0,
    const float* __restrict__ A1, const float* __restrict__ B1,
    const float* __restrict__ bias0, const float* __restrict__ bias1,
    float* __restrict__ C, int M, int K, int ldc)
{
    __shared__ _Float16 Ahi[GBM*AROWP];
    __shared__ _Float16 Bhi[GBN*AROWP];
    floatx4 zz = {0.f, 0.f, 0.f, 0.f};
    floatx4 acc[4][4];
    #pragma unroll
    for (int i = 0; i < 4; ++i)
        #pragma unroll
        for (int j = 0; j < 4; ++j) acc[i][j] = zz;
    const int tid = threadIdx.x;
    const int m0 = blockIdx.x*GBM;
    const int n0 = blockIdx.y*GBN;
    mfma_core<false>(A0, B0 + (size_t)n0*K, K, m0, 0, M, tid, acc, Ahi, nullptr, Bhi, nullptr);
    mfma_core<false>(A1, B1 + (size_t)n0*K, K, m0, 0, M, tid, acc, Ahi, nullptr, Bhi, nullptr);
    const int wv = tid >> 6, lane = tid & 63;
    const int wr = wv >> 1, wc = wv & 1;
    const int mloc = lane & 15, kb = lane >> 4;
    float bv[4];
    #pragma unroll
    for (int j = 0; j < 4; ++j){
        int cn = n0 + wc*64 + j*16 + mloc;
        bv[j] = bias0[cn] + bias1[cn];
    }
    #pragma unroll
    for (int i = 0; i < 4; ++i){
        #pragma unroll
        for (int r = 0; r < 4; ++r){
            int gm = m0 + wr*64 + i*16 + kb*4 + r;
            if (gm >= M) continue;
            #pragma unroll
            for (int j = 0; j < 4; ++j){
                int cn = n0 + wc*64 + j*16 + mloc;
                C[(size_t)gm*ldc + cn] = acc[i][j][r] + bv[j];
            }
        }
    }
}

// ---------------- conv GEMM (split MFMA) over taps + bias + LeakyReLU -> x_feat fp32 ----------------
__global__ __launch_bounds__(256) void k_conv_gemm(
    const float* __restrict__ xd, const float* __restrict__ wrep,
    const float* __restrict__ cb0, const float* __restrict__ cb1, const float* __restrict__ cb2,
    float* __restrict__ x_feat, int N)
{
    __shared__ _Float16 Ahi[GBM*AROWP], Alo[GBM*AROWP];
    __shared__ _Float16 Bhi[GBN*AROWP], Blo[GBN*AROWP];
    floatx4 zz = {0.f, 0.f, 0.f, 0.f};
    floatx4 acc[4][4];
    #pragma unroll
    for (int i = 0; i < 4; ++i)
        #pragma unroll
        for (int j = 0; j < 4; ++j) acc[i][j] = zz;
    const int tid = threadIdx.x;
    const int m0  = blockIdx.x*GBM;
    const int gid = blockIdx.y;            // 0..5
    const int g = gid >> 1, half = gid & 1;
    const int kg = (g==0)?3:((g==1)?5:7);
    const int p  = kg >> 1;
    const int tb = (g==0)?0:((g==1)?3:8);
    for (int t = 0; t < kg; ++t){
        const float* B = wrep + ((size_t)(tb + t)*256 + half*128)*DPAD;
        mfma_core<true>(xd, B, DPAD, m0, 4 + t - p, N + 8, tid, acc, Ahi, Alo, Bhi, Blo);
    }
    const float* cb = (g==0)?cb0:((g==1)?cb1:cb2);
    const int wv = tid >> 6, lane = tid & 63;
    const int wr = wv >> 1, wc = wv & 1;
    const int mloc = lane & 15, kb = lane >> 4;
    float bv[4];
    #pragma unroll
    for (int j = 0; j < 4; ++j) bv[j] = cb[half*128 + wc*64 + j*16 + mloc];
    const int colbase = g*256 + half*128 + wc*64 + mloc;
    #pragma unroll
    for (int i = 0; i < 4; ++i){
        #pragma unroll
        for (int r = 0; r < 4; ++r){
            int gm = m0 + wr*64 + i*16 + kb*4 + r;
            if (gm >= N) continue;
            float* crow = x_feat + (size_t)gm*HID + colbase;
            #pragma unroll
            for (int j = 0; j < 4; ++j){
                float y = acc[i][j][r] + bv[j];
                crow[j*16] = (y >= 0.f) ? y : 0.01f*y;
            }
        }
    }
}

// ---------------- maxpool (stride1, same) over activated conv output ----------------
__global__ void k_pool(const float* __restrict__ xf, float* __restrict__ xp, int N){
    int idx = blockIdx.x*256 + threadIdx.x;
    if (idx >= N*HID) return;
    int n = idx / HID, ch = idx - n*HID;
    int p = (ch < 256) ? 1 : ((ch < 512) ? 2 : 3);
    float m = -INFINITY;
    for (int d = -p; d <= p; ++d){
        int r = n + d;
        if (0 <= r && r < N) m = fmaxf(m, xf[(size_t)r*HID + ch]);
    }
    xp[idx] = m;
}

// ---------------- chunked LSTM scan: 96 persistent WGs, MFMA h-dot, fp16 h exchange ----------------
// Identical to the round-2 kernel that passed at absmax 0.0063 (h_all stored fp32).
__global__ __launch_bounds__(256, 1) void k_scan(
    const __half* __restrict__ G1, const float* __restrict__ W_hh,
    float* __restrict__ h_all, __half* __restrict__ c_all,
    __half* __restrict__ h_buf, unsigned int* __restrict__ flags,
    int N, int n_chunks)
{
    __shared__ __align__(16) __half hs16[16*HPAD];  // [chain][k] fp16, padded rows
    __shared__ float gbuf[2][32][17];               // [kh][row m][chain] partial gates
    const int w    = blockIdx.x;
    const int t    = threadIdx.x;
    const int lane = t & 63;
    const int wv   = t >> 6;              // wave 0..3
    const int mt   = wv & 1;              // M-tile (rows mt*16..mt*16+15)
    const int kh   = wv >> 1;             // K-half (k = kh*384 ..)
    const int mloc = lane & 15;           // A row within tile / B chain
    const int kb   = lane >> 4;           // k-subgroup (8 halfs each)
    const int mg   = mt*16 + mloc;        // local row 0..31
    const int qq   = mg >> 3;             // gate 0..3
    const int il   = mg & 7;              // h-index 0..7
    const int grow = qq*HID + w*8 + il;   // global W_hh row
    half8 areg[12];
    #pragma unroll
    for (int sk = 0; sk < 12; ++sk){
        const float* wp = W_hh + (size_t)grow*HID + kh*384 + sk*32 + kb*8;
        half8 a;
        #pragma unroll
        for (int e = 0; e < 8; ++e) a[e] = (_Float16)wp[e];
        areg[sk] = a;
    }
    float cstate = 0.f;
    const int ci = t >> 4;                // cell-phase h index (t<128)
    const int cc = t & 15;                // cell-phase chain
    for (int s = 0; s < n_chunks; ++s){
        // 0. prefetch this step's G1 gates (independent of h -> overlaps phases 1-2)
        float g1v0=0.f, g1v1=0.f, g1v2=0.f, g1v3=0.f;
        int n = s*16 + cc;
        if (t < 128 && n < N){
            const __half* g1r = G1 + (size_t)n*G4 + w*8 + ci;
            g1v0 = __half2float(g1r[0]);
            g1v1 = __half2float(g1r[HID]);
            g1v2 = __half2float(g1r[2*HID]);
            g1v3 = __half2float(g1r[3*HID]);
        }
        // 1. stage h (fp16 ping-pong) into LDS via coherent 8B relaxed-atomic loads
        {
            const unsigned long long* hsrc =
                (const unsigned long long*)(h_buf + (size_t)(s & 1)*(16*HPAD));
            unsigned long long* hdst = (unsigned long long*)hs16;
            for (int j = t; j < 16*HPAD/4; j += 256)
                hdst[j] = __hip_atomic_load(hsrc + j, __ATOMIC_RELAXED,
                                            __HIP_MEMORY_SCOPE_AGENT);
        }
        __syncthreads();
        // 2. MFMA: gates partial over this wave's K-half
        {
            floatx4 acc = {0.f, 0.f, 0.f, 0.f};
            const _Float16* hb = (const _Float16*)hs16;
            #pragma unroll
            for (int sk = 0; sk < 12; ++sk){
                int k0 = kh*384 + sk*32 + kb*8;
                half8 b = *(const half8*)(hb + (size_t)mloc*HPAD + k0);
                acc = __builtin_amdgcn_mfma_f32_16x16x32_f16(areg[sk], b, acc, 0, 0, 0);
            }
            #pragma unroll
            for (int r = 0; r < 4; ++r)
                gbuf[kh][mt*16 + kb*4 + r][mloc] = acc[r];
        }
        __syncthreads();
        // 3. cell math: 128 threads = 8 h-indices x 16 chains
        if (t < 128 && n < N){
            int col = w*8 + ci;
            float gI = gbuf[0][0*8+ci][cc] + gbuf[1][0*8+ci][cc] + g1v0;
            float gF = gbuf[0][1*8+ci][cc] + gbuf[1][1*8+ci][cc] + g1v1;
            float gG = gbuf[0][2*8+ci][cc] + gbuf[1][2*8+ci][cc] + g1v2;
            float gO = gbuf[0][3*8+ci][cc] + gbuf[1][3*8+ci][cc] + g1v3;
            float c2 = sigf(gF)*cstate + sigf(gI)*tanhf(gG);
            float h2 = sigf(gO)*tanhf(c2);
            cstate = c2;
            size_t rowoff = (size_t)(16 + n)*HID + col;
            h_all[rowoff] = h2;                       // fp32 (phase-4 GEMM input)
            c_all[rowoff] = __float2half(c2);
            unsigned hb2 = (unsigned)__half_as_ushort(__float2half(h2));
            unsigned other = __shfl_xor(hb2, 16, 64);  // partner t^16 = same cc, ci^1
            if ((ci & 1) == 0){
                unsigned pk = hb2 | (other << 16);     // even col = low half
                unsigned* dst = (unsigned*)h_buf +
                    (((size_t)((s+1)&1)*(16*HPAD) + (size_t)cc*HPAD + col) >> 1);
                __hip_atomic_store(dst, pk, __ATOMIC_RELAXED, __HIP_MEMORY_SCOPE_AGENT);
            }
        }
        // 4. distributed flag barrier across the 96 WGs (relaxed agent atomics only)
        __syncthreads();                  // drains vmcnt: phase-3 stores are at MALL
        if (t == 0)
            __hip_atomic_store(&flags[w*16], (unsigned)(s + 1),
                               __ATOMIC_RELAXED, __HIP_MEMORY_SCOPE_AGENT);
        if (t < NWG_SCAN){
            while (__hip_atomic_load(&flags[t*16], __ATOMIC_RELAXED,
                                     __HIP_MEMORY_SCOPE_AGENT) < (unsigned)(s + 1))
                __builtin_amdgcn_s_sleep(2);
        }
        __syncthreads();                  // everyone saw all 96 flags -> step s data ready
    }
}

// ---------------- final two LSTM cells (forward + rev weights) ----------------
__global__ void k_cell(const float* __restrict__ g2, const float* __restrict__ g3,
                       const __half* __restrict__ c_all, float* __restrict__ out,
                       int n0, int Mslab, int N){
    int idx = blockIdx.x*256 + threadIdx.x;
    if (idx >= Mslab*HID) return;
    int nl = idx / HID, j = idx - nl*HID;
    int n = n0 + nl;
    const float* r2 = g2 + (size_t)nl*G4;
    float cp = __half2float(c_all[(size_t)(7 + n)*HID + j]);   // c[n-9] (16-row pad, -9)
    float c2 = sigf(r2[HID + j])*cp + sigf(r2[j])*tanhf(r2[2*HID + j]);
    out[(size_t)n*1536 + j] = sigf(r2[3*HID + j])*tanhf(c2);
    const float* r3 = g3 + (size_t)nl*G4;
    float cn = __half2float(c_all[(size_t)(25 + n)*HID + j]);  // c[n+9]
    float c3 = sigf(r3[HID + j])*cn + sigf(r3[j])*tanhf(r3[2*HID + j]);
    out[(size_t)n*1536 + HID + j] = sigf(r3[3*HID + j])*tanhf(c3);
}

extern "C" void kernel_launch(void* const* d_in, const int* in_sizes, int n_in,
                              void* d_out, int out_size, void* d_ws, size_t ws_size,
                              hipStream_t stream)
{
    const float* x     = (const float*)d_in[0];
    const int*   dl    = (const int*)  d_in[1];
    const float* cw0   = (const float*)d_in[2];
    const float* cb0   = (const float*)d_in[3];
    const float* cw1   = (const float*)d_in[4];
    const float* cb1   = (const float*)d_in[5];
    const float* cw2   = (const float*)d_in[6];
    const float* cb2   = (const float*)d_in[7];
    const float* W_ih  = (const float*)d_in[8];
    const float* W_hh  = (const float*)d_in[9];
    const float* b_ih  = (const float*)d_in[10];
    const float* b_hh  = (const float*)d_in[11];
    const float* W_ihr = (const float*)d_in[12];
    const float* W_hhr = (const float*)d_in[13];
    const float* b_ihr = (const float*)d_in[14];
    const float* b_hhr = (const float*)d_in[15];
    float* out = (float*)d_out;
    (void)in_sizes; (void)n_in;
    const int N = out_size / (2*HID);
    if (N <= 0) return;
    const int n_chunks = (N + 15)/16;
    const int N16 = n_chunks*16;

    // ---- lifetime-overlaid arena (round-2 layout: fp32 activations) ----
    // R0 timeline: {xd fp32 + wrep fp32} -> {x_pool fp32} -> {h_all fp32 + c_all fp16}
    auto AL = [](size_t b){ return (b + 255) & ~(size_t)255; };
    const size_t szXd   = AL((size_t)(N+8)*DPAD*4);      // fp32 x_doc
    const size_t szW    = AL((size_t)15*256*DPAD*4);     // conv weights repacked fp32
    const size_t szPool = AL((size_t)N*HID*4);           // x_pool fp32
    const size_t szH    = AL((size_t)(N+32)*HID*4);      // h_all fp32
    const size_t szC    = AL((size_t)(N+32)*HID*2);      // c_all fp16
    size_t r0 = szXd + szW;
    if (szPool     > r0) r0 = szPool;
    if (szH + szC  > r0) r0 = szH + szC;
    const size_t szF    = AL((size_t)N*HID*4);           // x_feat fp32 (alive to end)
    size_t szG1 = AL((size_t)N16*G4*2);                  // fp16 G1 | later g2+g3 fp32
    const size_t szGG   = AL((size_t)SLAB*G4*4);
    if (2*szGG > szG1) szG1 = 2*szGG;
    const size_t szHB   = AL((size_t)2*16*HPAD*2);       // h ping-pong (fp16, padded rows)
    const size_t szFL   = AL((size_t)NWG_SCAN*16*4);     // flags, 64B-padded
    const size_t szPI   = AL((size_t)N*4);               // pos_idx

    char* wsb = (char*)d_ws;
    size_t off = 0;
    char* R0   = wsb;              off += r0;
    char* pF   = wsb + off;        off += szF;
    char* pG1  = wsb + off;        off += szG1;
    char* pHB  = wsb + off;        off += szHB;
    char* pFL  = wsb + off;        off += szFL;
    char* pPI  = wsb + off;        off += szPI;
    if (off > ws_size) return;     // workspace too small: fail loud (wrong answer), not a fault

    float*          xd    = (float*)R0;
    float*          wrep  = (float*)(R0 + szXd);
    float*          x_pool= (float*)R0;                  // overlays xd/wrep after conv
    float*          h_all = (float*)R0;                  // overlays x_pool after G1 GEMM
    __half*         c_all = (__half*)(R0 + szH);         // beside h_all in R0 slack
    float*          x_feat= (float*)pF;
    __half*         G1    = (__half*)pG1;
    float*          g2    = (float*)pG1;                 // overlays G1 after scan
    float*          g3    = (float*)(pG1 + szGG);
    __half*         h_buf = (__half*)pHB;
    unsigned*       flags = (unsigned*)pFL;
    int*            pos_idx = (int*)pPI;

    // ---- phase 1: x_doc fp32 + conv weight repack + conv (split MFMA) + pool ----
    hipMemsetAsync(xd, 0, (size_t)4*DPAD*4, stream);                       // top pad rows
    hipMemsetAsync(xd + (size_t)(N+4)*DPAD, 0, (size_t)4*DPAD*4, stream);  // bottom pad rows
    k_prep<<<1, 128, 0, stream>>>(dl, pos_idx, N);
    k_fill_xdoc<<<(N*DPAD + 255)/256, 256, 0, stream>>>(x, pos_idx, xd, N);
    k_repack_w<<<(15*256*DPAD + 255)/256, 256, 0, stream>>>(cw0, cw1, cw2, wrep);

    const int mt = (N + GBM - 1)/GBM;
    k_conv_gemm<<<dim3(mt, 6), 256, 0, stream>>>(xd, wrep, cb0, cb1, cb2, x_feat, N);
    k_pool<<<(N*HID + 255)/256, 256, 0, stream>>>(x_feat, x_pool, N);      // x_pool overlays xd

    // ---- phase 2: G1 = x_pool*W_ih^T + b_ih + b_hh (split MFMA, fp16 out) ----
    k_gemm_split<true><<<dim3(mt, G4/GBN), 256, 0, stream>>>(
        x_pool, W_ih, b_ih, b_hh, G1, N, HID, G4);

    // ---- phase 3: scan (h_all/c_all overlay x_pool region — pads zeroed only now) ----
    hipMemsetAsync(h_all, 0, (size_t)16*HID*4, stream);
    hipMemsetAsync(h_all + (size_t)(16+N)*HID, 0, (size_t)16*HID*4, stream);
    hipMemsetAsync(c_all, 0, (size_t)16*HID*2, stream);
    hipMemsetAsync(c_all + (size_t)(16+N)*HID, 0, (size_t)16*HID*2, stream);
    hipMemsetAsync(h_buf, 0, (size_t)2*16*HPAD*2, stream);
    hipMemsetAsync(flags, 0, szFL, stream);
    k_scan<<<NWG_SCAN, 256, 0, stream>>>(G1, W_hh, h_all, c_all, h_buf, flags, N, n_chunks);

    // ---- phase 4: final two cells, slabbed (g2/g3 overlay G1 region; plain fp16 MFMA) ----
    for (int n0 = 0; n0 < N; n0 += SLAB){
        int ms  = (N - n0 < SLAB) ? (N - n0) : SLAB;
        int mts = (ms + GBM - 1)/GBM;
        k_gemm_plain2<<<dim3(mts, G4/GBN), 256, 0, stream>>>(
            x_feat + (size_t)n0*HID, W_ih, h_all + (size_t)(7+n0)*HID, W_hh,
            b_ih, b_hh, g2, ms, HID, G4);
        k_gemm_plain2<<<dim3(mts, G4/GBN), 256, 0, stream>>>(
            x_feat + (size_t)n0*HID, W_ihr, h_all + (size_t)(25+n0)*HID, W_hhr,
            b_ihr, b_hhr, g3, ms, HID, G4);
        k_cell<<<(ms*HID + 255)/256, 256, 0, stream>>>(g2, g3, c_all, out, n0, ms, N);
    }
}

// Round 6
// 6606.343 us; speedup vs baseline: 5.9562x; 1.2498x over previous
//
#include <hip/hip_runtime.h>
#include <hip/hip_bf16.h>
#include <hip/hip_fp16.h>
#include <math.h>

#define DIN   1068
#define DPAD  1088
#define HID   768
#define G4    3072
#define NWG_SCAN 96
#define SLAB  2048
#define HPAD  776   // 768 + 8 halfs pad for scan LDS
#define GBM   128
#define GBN   128
#define AROWP 40    // LDS row pitch in halfs: 32 + 8 pad

typedef _Float16 half8 __attribute__((ext_vector_type(8)));
typedef float    floatx4 __attribute__((ext_vector_type(4)));

__device__ __forceinline__ float sigf(float x){ return 1.0f/(1.0f + expf(-x)); }

// ---------------- prep: doc offsets -> per-position index within doc ----------------
__global__ void k_prep(const int* __restrict__ doc_lens, int* __restrict__ pos_idx, int N){
    __shared__ int off[129];
    if (threadIdx.x == 0){
        int a = 0;
        for (int d = 0; d < 128; ++d){ off[d] = a; a += doc_lens[d]; }
        off[128] = a;
    }
    __syncthreads();
    for (int d = threadIdx.x; d < 128; d += blockDim.x){
        int s = off[d], e = off[d+1];
        for (int n = s; n < e && n < N; ++n) pos_idx[n] = n - s;
    }
}

// ---------------- x_doc = x + PE(pos) (fp32), rows offset +4, cols 1068->1088 ----------------
__global__ void k_fill_xdoc(const float* __restrict__ x, const int* __restrict__ pos_idx,
                            float* __restrict__ xd, int N){
    int idx = blockIdx.x*256 + threadIdx.x;
    int total = N * DPAD;
    if (idx >= total) return;
    int n = idx / DPAD;
    int d = idx - n*DPAD;
    float v = 0.f;
    if (d < DIN){
        int pos = pos_idx[n];
        int i2 = d & ~1;                      // 2*i for both sin (even d) and cos (odd d)
        float ex  = expf(-(float)i2 * (9.210340371976184f / 1068.0f)); // 10000^(-i2/1068)
        float ang = (float)pos * ex;
        v = x[(size_t)n*DIN + d] + ((d & 1) ? cosf(ang) : sinf(ang));
    }
    xd[(size_t)(n+4)*DPAD + d] = v;
}

// ---------------- repack conv weights [oc][d][t] -> [tau][oc][dpad] (fp32) ----------------
__global__ void k_repack_w(const float* __restrict__ w0, const float* __restrict__ w1,
                           const float* __restrict__ w2, float* __restrict__ wrep){
    int idx = blockIdx.x*256 + threadIdx.x;
    const int total = 15*256*DPAD;
    if (idx >= total) return;
    int d    = idx % DPAD;
    int rest = idx / DPAD;
    int oc   = rest % 256;
    int tau  = rest / 256;
    const float* w; int k, t;
    if (tau < 3)      { w = w0; k = 3; t = tau;     }
    else if (tau < 8) { w = w1; k = 5; t = tau - 3; }
    else              { w = w2; k = 7; t = tau - 8; }
    float v = 0.f;
    if (d < DIN) v = w[((size_t)oc*DIN + d)*k + t];
    wrep[(size_t)idx] = v;
}

// ---------------- MFMA tile core over fp32 operands ----------------
// A,B fp32 row-major [*, K]; B pre-offset to its 128-row block. K % 32 == 0.
// Staging converts fp32 -> fp16 {hi[,lo]} in LDS. SPLIT=true computes
// hi*hi + hi*lo + lo*hi (3 MFMAs, fp32-equivalent precision, rel err ~2^-22);
// SPLIT=false computes hi*hi only (plain fp16 precision).
// 256 thr = 4 waves in 2x2, per-wave 64x64 output as 4x4 frags of 16x16x32_f16.
// Operand layout validated on HW by rounds 1-3: A/B lane l: row (l&15), k-base
// (l>>4)*8; D: col = lane&15, row = (lane>>4)*4 + r.
template<bool SPLIT>
__device__ __forceinline__ void mfma_core(
    const float* __restrict__ A, const float* __restrict__ B, int K,
    int m0, int shift, int rowcap, int tid, floatx4 (&acc)[4][4],
    _Float16* __restrict__ Ahi, _Float16* __restrict__ Alo,
    _Float16* __restrict__ Bhi, _Float16* __restrict__ Blo)
{
    const int st_r = tid >> 1;            // staged row 0..127
    const int st_s = (tid & 1) * 16;      // k-offset 0 or 16 (floats)
    const int wv = tid >> 6, lane = tid & 63;
    const int wr = wv >> 1, wc = wv & 1;
    const int mloc = lane & 15, kb = lane >> 4;
    for (int k0 = 0; k0 < K; k0 += 32){
        // ---- stage A (guarded rows) ----
        {
            float av[16] = {};
            int r = m0 + st_r + shift;
            if ((unsigned)r < (unsigned)rowcap){
                const float* pa = A + (size_t)r*K + k0 + st_s;
                *(float4*)&av[0]  = *(const float4*)pa;
                *(float4*)&av[4]  = *(const float4*)(pa+4);
                *(float4*)&av[8]  = *(const float4*)(pa+8);
                *(float4*)&av[12] = *(const float4*)(pa+12);
            }
            #pragma unroll
            for (int g = 0; g < 2; ++g){
                half8 hh, hl;
                #pragma unroll
                for (int e = 0; e < 8; ++e){
                    float f = av[g*8+e];
                    _Float16 h = (_Float16)f;
                    hh[e] = h;
                    if (SPLIT) hl[e] = (_Float16)(f - (float)h);
                }
                *(half8*)&Ahi[st_r*AROWP + st_s + g*8] = hh;
                if (SPLIT) *(half8*)&Alo[st_r*AROWP + st_s + g*8] = hl;
            }
        }
        // ---- stage B (always valid) ----
        {
            float bv[16];
            const float* pb = B + (size_t)st_r*K + k0 + st_s;
            *(float4*)&bv[0]  = *(const float4*)pb;
            *(float4*)&bv[4]  = *(const float4*)(pb+4);
            *(float4*)&bv[8]  = *(const float4*)(pb+8);
            *(float4*)&bv[12] = *(const float4*)(pb+12);
            #pragma unroll
            for (int g = 0; g < 2; ++g){
                half8 hh, hl;
                #pragma unroll
                for (int e = 0; e < 8; ++e){
                    float f = bv[g*8+e];
                    _Float16 h = (_Float16)f;
                    hh[e] = h;
                    if (SPLIT) hl[e] = (_Float16)(f - (float)h);
                }
                *(half8*)&Bhi[st_r*AROWP + st_s + g*8] = hh;
                if (SPLIT) *(half8*)&Blo[st_r*AROWP + st_s + g*8] = hl;
            }
        }
        __syncthreads();
        half8 afh[4], bfh[4], afl[4], bfl[4];
        #pragma unroll
        for (int i = 0; i < 4; ++i){
            afh[i] = *(const half8*)&Ahi[(wr*64 + i*16 + mloc)*AROWP + kb*8];
            bfh[i] = *(const half8*)&Bhi[(wc*64 + i*16 + mloc)*AROWP + kb*8];
            if (SPLIT){
                afl[i] = *(const half8*)&Alo[(wr*64 + i*16 + mloc)*AROWP + kb*8];
                bfl[i] = *(const half8*)&Blo[(wc*64 + i*16 + mloc)*AROWP + kb*8];
            }
        }
        #pragma unroll
        for (int i = 0; i < 4; ++i)
            #pragma unroll
            for (int j = 0; j < 4; ++j){
                acc[i][j] = __builtin_amdgcn_mfma_f32_16x16x32_f16(afh[i], bfh[j], acc[i][j], 0, 0, 0);
                if (SPLIT){
                    acc[i][j] = __builtin_amdgcn_mfma_f32_16x16x32_f16(afh[i], bfl[j], acc[i][j], 0, 0, 0);
                    acc[i][j] = __builtin_amdgcn_mfma_f32_16x16x32_f16(afl[i], bfh[j], acc[i][j], 0, 0, 0);
                }
            }
        __syncthreads();
    }
}

// ---------------- split-precision GEMM: C = A0*B0^T + bias0 (+bias1); fp32-quality ----------------
template<bool CHALF>
__global__ __launch_bounds__(256) void k_gemm_split(
    const float* __restrict__ A0, const float* __restrict__ B0,
    const float* __restrict__ bias0, const float* __restrict__ bias1,
    void* __restrict__ C, int M, int K, int ldc)
{
    __shared__ _Float16 Ahi[GBM*AROWP], Alo[GBM*AROWP];
    __shared__ _Float16 Bhi[GBN*AROWP], Blo[GBN*AROWP];
    floatx4 zz = {0.f, 0.f, 0.f, 0.f};
    floatx4 acc[4][4];
    #pragma unroll
    for (int i = 0; i < 4; ++i)
        #pragma unroll
        for (int j = 0; j < 4; ++j) acc[i][j] = zz;
    const int tid = threadIdx.x;
    const int m0 = blockIdx.x*GBM;
    const int n0 = blockIdx.y*GBN;
    mfma_core<true>(A0, B0 + (size_t)n0*K, K, m0, 0, M, tid, acc, Ahi, Alo, Bhi, Blo);
    const int wv = tid >> 6, lane = tid & 63;
    const int wr = wv >> 1, wc = wv & 1;
    const int mloc = lane & 15, kb = lane >> 4;
    float bv[4];
    #pragma unroll
    for (int j = 0; j < 4; ++j){
        int cn = n0 + wc*64 + j*16 + mloc;
        bv[j] = bias0[cn] + (bias1 ? bias1[cn] : 0.f);
    }
    #pragma unroll
    for (int i = 0; i < 4; ++i){
        #pragma unroll
        for (int r = 0; r < 4; ++r){
            int gm = m0 + wr*64 + i*16 + kb*4 + r;
            if (gm >= M) continue;
            #pragma unroll
            for (int j = 0; j < 4; ++j){
                int cn = n0 + wc*64 + j*16 + mloc;
                float v = acc[i][j][r] + bv[j];
                if (CHALF) ((__half*)C)[(size_t)gm*ldc + cn] = __float2half(v);
                else       ((float*)C)[(size_t)gm*ldc + cn] = v;
            }
        }
    }
}

// ---------------- plain fp16 GEMM (fp32 in): C = A0*B0^T + A1*B1^T + bias0 + bias1 ----------------
__global__ __launch_bounds__(256) void k_gemm_plain2(
    const float* __restrict__ A0, const float* __restrict__ B0,
    const float* __restrict__ A1, const float* __restrict__ B1,
    const float* __restrict__ bias0, const float* __restrict__ bias1,
    float* __restrict__ C, int M, int K, int ldc)
{
    __shared__ _Float16 Ahi[GBM*AROWP];
    __shared__ _Float16 Bhi[GBN*AROWP];
    floatx4 zz = {0.f, 0.f, 0.f, 0.f};
    floatx4 acc[4][4];
    #pragma unroll
    for (int i = 0; i < 4; ++i)
        #pragma unroll
        for (int j = 0; j < 4; ++j) acc[i][j] = zz;
    const int tid = threadIdx.x;
    const int m0 = blockIdx.x*GBM;
    const int n0 = blockIdx.y*GBN;
    mfma_core<false>(A0, B0 + (size_t)n0*K, K, m0, 0, M, tid, acc, Ahi, nullptr, Bhi, nullptr);
    mfma_core<false>(A1, B1 + (size_t)n0*K, K, m0, 0, M, tid, acc, Ahi, nullptr, Bhi, nullptr);
    const int wv = tid >> 6, lane = tid & 63;
    const int wr = wv >> 1, wc = wv & 1;
    const int mloc = lane & 15, kb = lane >> 4;
    float bv[4];
    #pragma unroll
    for (int j = 0; j < 4; ++j){
        int cn = n0 + wc*64 + j*16 + mloc;
        bv[j] = bias0[cn] + bias1[cn];
    }
    #pragma unroll
    for (int i = 0; i < 4; ++i){
        #pragma unroll
        for (int r = 0; r < 4; ++r){
            int gm = m0 + wr*64 + i*16 + kb*4 + r;
            if (gm >= M) continue;
            #pragma unroll
            for (int j = 0; j < 4; ++j){
                int cn = n0 + wc*64 + j*16 + mloc;
                C[(size_t)gm*ldc + cn] = acc[i][j][r] + bv[j];
            }
        }
    }
}

// ---------------- conv GEMM (split MFMA) over taps + bias + LeakyReLU -> x_feat fp32 ----------------
__global__ __launch_bounds__(256) void k_conv_gemm(
    const float* __restrict__ xd, const float* __restrict__ wrep,
    const float* __restrict__ cb0, const float* __restrict__ cb1, const float* __restrict__ cb2,
    float* __restrict__ x_feat, int N)
{
    __shared__ _Float16 Ahi[GBM*AROWP], Alo[GBM*AROWP];
    __shared__ _Float16 Bhi[GBN*AROWP], Blo[GBN*AROWP];
    floatx4 zz = {0.f, 0.f, 0.f, 0.f};
    floatx4 acc[4][4];
    #pragma unroll
    for (int i = 0; i < 4; ++i)
        #pragma unroll
        for (int j = 0; j < 4; ++j) acc[i][j] = zz;
    const int tid = threadIdx.x;
    const int m0  = blockIdx.x*GBM;
    const int gid = blockIdx.y;            // 0..5
    const int g = gid >> 1, half = gid & 1;
    const int kg = (g==0)?3:((g==1)?5:7);
    const int p  = kg >> 1;
    const int tb = (g==0)?0:((g==1)?3:8);
    for (int t = 0; t < kg; ++t){
        const float* B = wrep + ((size_t)(tb + t)*256 + half*128)*DPAD;
        mfma_core<true>(xd, B, DPAD, m0, 4 + t - p, N + 8, tid, acc, Ahi, Alo, Bhi, Blo);
    }
    const float* cb = (g==0)?cb0:((g==1)?cb1:cb2);
    const int wv = tid >> 6, lane = tid & 63;
    const int wr = wv >> 1, wc = wv & 1;
    const int mloc = lane & 15, kb = lane >> 4;
    float bv[4];
    #pragma unroll
    for (int j = 0; j < 4; ++j) bv[j] = cb[half*128 + wc*64 + j*16 + mloc];
    const int colbase = g*256 + half*128 + wc*64 + mloc;
    #pragma unroll
    for (int i = 0; i < 4; ++i){
        #pragma unroll
        for (int r = 0; r < 4; ++r){
            int gm = m0 + wr*64 + i*16 + kb*4 + r;
            if (gm >= N) continue;
            float* crow = x_feat + (size_t)gm*HID + colbase;
            #pragma unroll
            for (int j = 0; j < 4; ++j){
                float y = acc[i][j][r] + bv[j];
                crow[j*16] = (y >= 0.f) ? y : 0.01f*y;
            }
        }
    }
}

// ---------------- maxpool (stride1, same) over activated conv output ----------------
__global__ void k_pool(const float* __restrict__ xf, float* __restrict__ xp, int N){
    int idx = blockIdx.x*256 + threadIdx.x;
    if (idx >= N*HID) return;
    int n = idx / HID, ch = idx - n*HID;
    int p = (ch < 256) ? 1 : ((ch < 512) ? 2 : 3);
    float m = -INFINITY;
    for (int d = -p; d <= p; ++d){
        int r = n + d;
        if (0 <= r && r < N) m = fmaxf(m, xf[(size_t)r*HID + ch]);
    }
    xp[idx] = m;
}

// ---------------- chunked LSTM scan: 96 persistent WGs, MFMA h-dot, fp16 h exchange ----------------
// This revision fixes the h-staging serialization: the old rolled loop
// (atomic load -> waitcnt -> ds_write, 12-13 iterations) serialized 12 MALL
// round-trips (~900cy each ~= 5.1us of the 5.9us step). Now h_buf is compact
// (16x768 halfs = 3072 8B words = 12 words x 256 threads exactly), and the
// stage does 12 fully-unrolled independent atomic loads into registers, then
// 12 LDS writes -> ~1 MALL RTT total. LDS layout (HPAD-padded) is unchanged.
__global__ __launch_bounds__(256, 1) void k_scan(
    const __half* __restrict__ G1, const float* __restrict__ W_hh,
    float* __restrict__ h_all, __half* __restrict__ c_all,
    __half* __restrict__ h_buf, unsigned int* __restrict__ flags,
    int N, int n_chunks)
{
    __shared__ __align__(16) __half hs16[16*HPAD];  // [chain][k] fp16, padded rows
    __shared__ float gbuf[2][32][17];               // [kh][row m][chain] partial gates
    const int w    = blockIdx.x;
    const int t    = threadIdx.x;
    const int lane = t & 63;
    const int wv   = t >> 6;              // wave 0..3
    const int mt   = wv & 1;              // M-tile (rows mt*16..mt*16+15)
    const int kh   = wv >> 1;             // K-half (k = kh*384 ..)
    const int mloc = lane & 15;           // A row within tile / B chain
    const int kb   = lane >> 4;           // k-subgroup (8 halfs each)
    const int mg   = mt*16 + mloc;        // local row 0..31
    const int qq   = mg >> 3;             // gate 0..3
    const int il   = mg & 7;              // h-index 0..7
    const int grow = qq*HID + w*8 + il;   // global W_hh row
    half8 areg[12];
    #pragma unroll
    for (int sk = 0; sk < 12; ++sk){
        const float* wp = W_hh + (size_t)grow*HID + kh*384 + sk*32 + kb*8;
        half8 a;
        #pragma unroll
        for (int e = 0; e < 8; ++e) a[e] = (_Float16)wp[e];
        areg[sk] = a;
    }
    float cstate = 0.f;
    const int ci = t >> 4;                // cell-phase h index (t<128)
    const int cc = t & 15;                // cell-phase chain
    const int st_row = t >> 4;            // staging row 0..15
    const int st_wq  = (t & 15) * 12;     // staging 8B-word col 0..180 (192/row)
    for (int s = 0; s < n_chunks; ++s){
        // 0. prefetch this step's G1 gates (independent of h -> overlaps phases 1-2)
        float g1v0=0.f, g1v1=0.f, g1v2=0.f, g1v3=0.f;
        int n = s*16 + cc;
        if (t < 128 && n < N){
            const __half* g1r = G1 + (size_t)n*G4 + w*8 + ci;
            g1v0 = __half2float(g1r[0]);
            g1v1 = __half2float(g1r[HID]);
            g1v2 = __half2float(g1r[2*HID]);
            g1v3 = __half2float(g1r[3*HID]);
        }
        // 1. stage h (fp16 ping-pong) into LDS: 12 unrolled independent atomic
        //    loads -> regs (1 MALL RTT pipelined), then 12 LDS writes.
        {
            const unsigned long long* hsrc =
                (const unsigned long long*)(h_buf + (size_t)(s & 1)*(16*HID))
                + (size_t)st_row*192 + st_wq;
            unsigned long long tmp[12];
            #pragma unroll
            for (int i = 0; i < 12; ++i)
                tmp[i] = __hip_atomic_load(hsrc + i, __ATOMIC_RELAXED,
                                           __HIP_MEMORY_SCOPE_AGENT);
            unsigned long long* hrow =
                (unsigned long long*)(hs16 + (size_t)st_row*HPAD) + st_wq;
            #pragma unroll
            for (int i = 0; i < 12; ++i) hrow[i] = tmp[i];
        }
        __syncthreads();
        // 2. MFMA: gates partial over this wave's K-half
        {
            floatx4 acc = {0.f, 0.f, 0.f, 0.f};
            const _Float16* hb = (const _Float16*)hs16;
            #pragma unroll
            for (int sk = 0; sk < 12; ++sk){
                int k0 = kh*384 + sk*32 + kb*8;
                half8 b = *(const half8*)(hb + (size_t)mloc*HPAD + k0);
                acc = __builtin_amdgcn_mfma_f32_16x16x32_f16(areg[sk], b, acc, 0, 0, 0);
            }
            #pragma unroll
            for (int r = 0; r < 4; ++r)
                gbuf[kh][mt*16 + kb*4 + r][mloc] = acc[r];
        }
        __syncthreads();
        // 3. cell math: 128 threads = 8 h-indices x 16 chains
        if (t < 128 && n < N){
            int col = w*8 + ci;
            float gI = gbuf[0][0*8+ci][cc] + gbuf[1][0*8+ci][cc] + g1v0;
            float gF = gbuf[0][1*8+ci][cc] + gbuf[1][1*8+ci][cc] + g1v1;
            float gG = gbuf[0][2*8+ci][cc] + gbuf[1][2*8+ci][cc] + g1v2;
            float gO = gbuf[0][3*8+ci][cc] + gbuf[1][3*8+ci][cc] + g1v3;
            float c2 = sigf(gF)*cstate + sigf(gI)*tanhf(gG);
            float h2 = sigf(gO)*tanhf(c2);
            cstate = c2;
            size_t rowoff = (size_t)(16 + n)*HID + col;
            h_all[rowoff] = h2;                       // fp32 (phase-4 GEMM input)
            c_all[rowoff] = __float2half(c2);
            unsigned hb2 = (unsigned)__half_as_ushort(__float2half(h2));
            unsigned other = __shfl_xor(hb2, 16, 64);  // partner t^16 = same cc, ci^1
            if ((ci & 1) == 0){
                unsigned pk = hb2 | (other << 16);     // even col = low half
                unsigned* dst = (unsigned*)h_buf +
                    (((size_t)((s+1)&1)*(16*HID) + (size_t)cc*HID + col) >> 1);
                __hip_atomic_store(dst, pk, __ATOMIC_RELAXED, __HIP_MEMORY_SCOPE_AGENT);
            }
        }
        // 4. distributed flag barrier across the 96 WGs (relaxed agent atomics only)
        __syncthreads();                  // drains vmcnt: phase-3 stores are at MALL
        if (t == 0)
            __hip_atomic_store(&flags[w*16], (unsigned)(s + 1),
                               __ATOMIC_RELAXED, __HIP_MEMORY_SCOPE_AGENT);
        if (t < NWG_SCAN){
            while (__hip_atomic_load(&flags[t*16], __ATOMIC_RELAXED,
                                     __HIP_MEMORY_SCOPE_AGENT) < (unsigned)(s + 1))
                __builtin_amdgcn_s_sleep(1);
        }
        __syncthreads();                  // everyone saw all 96 flags -> step s data ready
    }
}

// ---------------- final two LSTM cells (forward + rev weights) ----------------
__global__ void k_cell(const float* __restrict__ g2, const float* __restrict__ g3,
                       const __half* __restrict__ c_all, float* __restrict__ out,
                       int n0, int Mslab, int N){
    int idx = blockIdx.x*256 + threadIdx.x;
    if (idx >= Mslab*HID) return;
    int nl = idx / HID, j = idx - nl*HID;
    int n = n0 + nl;
    const float* r2 = g2 + (size_t)nl*G4;
    float cp = __half2float(c_all[(size_t)(7 + n)*HID + j]);   // c[n-9] (16-row pad, -9)
    float c2 = sigf(r2[HID + j])*cp + sigf(r2[j])*tanhf(r2[2*HID + j]);
    out[(size_t)n*1536 + j] = sigf(r2[3*HID + j])*tanhf(c2);
    const float* r3 = g3 + (size_t)nl*G4;
    float cn = __half2float(c_all[(size_t)(25 + n)*HID + j]);  // c[n+9]
    float c3 = sigf(r3[HID + j])*cn + sigf(r3[j])*tanhf(r3[2*HID + j]);
    out[(size_t)n*1536 + HID + j] = sigf(r3[3*HID + j])*tanhf(c3);
}

extern "C" void kernel_launch(void* const* d_in, const int* in_sizes, int n_in,
                              void* d_out, int out_size, void* d_ws, size_t ws_size,
                              hipStream_t stream)
{
    const float* x     = (const float*)d_in[0];
    const int*   dl    = (const int*)  d_in[1];
    const float* cw0   = (const float*)d_in[2];
    const float* cb0   = (const float*)d_in[3];
    const float* cw1   = (const float*)d_in[4];
    const float* cb1   = (const float*)d_in[5];
    const float* cw2   = (const float*)d_in[6];
    const float* cb2   = (const float*)d_in[7];
    const float* W_ih  = (const float*)d_in[8];
    const float* W_hh  = (const float*)d_in[9];
    const float* b_ih  = (const float*)d_in[10];
    const float* b_hh  = (const float*)d_in[11];
    const float* W_ihr = (const float*)d_in[12];
    const float* W_hhr = (const float*)d_in[13];
    const float* b_ihr = (const float*)d_in[14];
    const float* b_hhr = (const float*)d_in[15];
    float* out = (float*)d_out;
    (void)in_sizes; (void)n_in;
    const int N = out_size / (2*HID);
    if (N <= 0) return;
    const int n_chunks = (N + 15)/16;
    const int N16 = n_chunks*16;

    // ---- lifetime-overlaid arena (fp32 activations) ----
    // R0 timeline: {xd fp32 + wrep fp32} -> {x_pool fp32} -> {h_all fp32 + c_all fp16}
    auto AL = [](size_t b){ return (b + 255) & ~(size_t)255; };
    const size_t szXd   = AL((size_t)(N+8)*DPAD*4);      // fp32 x_doc
    const size_t szW    = AL((size_t)15*256*DPAD*4);     // conv weights repacked fp32
    const size_t szPool = AL((size_t)N*HID*4);           // x_pool fp32
    const size_t szH    = AL((size_t)(N+32)*HID*4);      // h_all fp32
    const size_t szC    = AL((size_t)(N+32)*HID*2);      // c_all fp16
    size_t r0 = szXd + szW;
    if (szPool     > r0) r0 = szPool;
    if (szH + szC  > r0) r0 = szH + szC;
    const size_t szF    = AL((size_t)N*HID*4);           // x_feat fp32 (alive to end)
    size_t szG1 = AL((size_t)N16*G4*2);                  // fp16 G1 | later g2+g3 fp32
    const size_t szGG   = AL((size_t)SLAB*G4*4);
    if (2*szGG > szG1) szG1 = 2*szGG;
    const size_t szHB   = AL((size_t)2*16*HID*2);        // h ping-pong (fp16, compact)
    const size_t szFL   = AL((size_t)NWG_SCAN*16*4);     // flags, 64B-padded
    const size_t szPI   = AL((size_t)N*4);               // pos_idx

    char* wsb = (char*)d_ws;
    size_t off = 0;
    char* R0   = wsb;              off += r0;
    char* pF   = wsb + off;        off += szF;
    char* pG1  = wsb + off;        off += szG1;
    char* pHB  = wsb + off;        off += szHB;
    char* pFL  = wsb + off;        off += szFL;
    char* pPI  = wsb + off;        off += szPI;
    if (off > ws_size) return;     // workspace too small: fail loud (wrong answer), not a fault

    float*          xd    = (float*)R0;
    float*          wrep  = (float*)(R0 + szXd);
    float*          x_pool= (float*)R0;                  // overlays xd/wrep after conv
    float*          h_all = (float*)R0;                  // overlays x_pool after G1 GEMM
    __half*         c_all = (__half*)(R0 + szH);         // beside h_all in R0 slack
    float*          x_feat= (float*)pF;
    __half*         G1    = (__half*)pG1;
    float*          g2    = (float*)pG1;                 // overlays G1 after scan
    float*          g3    = (float*)(pG1 + szGG);
    __half*         h_buf = (__half*)pHB;
    unsigned*       flags = (unsigned*)pFL;
    int*            pos_idx = (int*)pPI;

    // ---- phase 1: x_doc fp32 + conv weight repack + conv (split MFMA) + pool ----
    hipMemsetAsync(xd, 0, (size_t)4*DPAD*4, stream);                       // top pad rows
    hipMemsetAsync(xd + (size_t)(N+4)*DPAD, 0, (size_t)4*DPAD*4, stream);  // bottom pad rows
    k_prep<<<1, 128, 0, stream>>>(dl, pos_idx, N);
    k_fill_xdoc<<<(N*DPAD + 255)/256, 256, 0, stream>>>(x, pos_idx, xd, N);
    k_repack_w<<<(15*256*DPAD + 255)/256, 256, 0, stream>>>(cw0, cw1, cw2, wrep);

    const int mt = (N + GBM - 1)/GBM;
    k_conv_gemm<<<dim3(mt, 6), 256, 0, stream>>>(xd, wrep, cb0, cb1, cb2, x_feat, N);
    k_pool<<<(N*HID + 255)/256, 256, 0, stream>>>(x_feat, x_pool, N);      // x_pool overlays xd

    // ---- phase 2: G1 = x_pool*W_ih^T + b_ih + b_hh (split MFMA, fp16 out) ----
    k_gemm_split<true><<<dim3(mt, G4/GBN), 256, 0, stream>>>(
        x_pool, W_ih, b_ih, b_hh, G1, N, HID, G4);

    // ---- phase 3: scan (h_all/c_all overlay x_pool region — pads zeroed only now) ----
    hipMemsetAsync(h_all, 0, (size_t)16*HID*4, stream);
    hipMemsetAsync(h_all + (size_t)(16+N)*HID, 0, (size_t)16*HID*4, stream);
    hipMemsetAsync(c_all, 0, (size_t)16*HID*2, stream);
    hipMemsetAsync(c_all + (size_t)(16+N)*HID, 0, (size_t)16*HID*2, stream);
    hipMemsetAsync(h_buf, 0, (size_t)2*16*HID*2, stream);
    hipMemsetAsync(flags, 0, szFL, stream);
    k_scan<<<NWG_SCAN, 256, 0, stream>>>(G1, W_hh, h_all, c_all, h_buf, flags, N, n_chunks);

    // ---- phase 4: final two cells, slabbed (g2/g3 overlay G1 region; plain fp16 MFMA) ----
    for (int n0 = 0; n0 < N; n0 += SLAB){
        int ms  = (N - n0 < SLAB) ? (N - n0) : SLAB;
        int mts = (ms + GBM - 1)/GBM;
        k_gemm_plain2<<<dim3(mts, G4/GBN), 256, 0, stream>>>(
            x_feat + (size_t)n0*HID, W_ih, h_all + (size_t)(7+n0)*HID, W_hh,
            b_ih, b_hh, g2, ms, HID, G4);
        k_gemm_plain2<<<dim3(mts, G4/GBN), 256, 0, stream>>>(
            x_feat + (size_t)n0*HID, W_ihr, h_all + (size_t)(25+n0)*HID, W_hhr,
            b_ihr, b_hhr, g3, ms, HID, G4);
        k_cell<<<(ms*HID + 255)/256, 256, 0, stream>>>(g2, g3, c_all, out, n0, ms, N);
    }
}